// Round 5
// baseline (1179.271 us; speedup 1.0000x reference)
//
#include <hip/hip_runtime.h>
#include <hip/hip_bf16.h>
#include <math.h>

#define NN 100000
#define EE 1000000
#define GG 64
#define BN_EPS 1e-5f
#define SB 512  // scan block size
#define CPB 16  // pooling chunks per graph

typedef __attribute__((ext_vector_type(8))) short bf16x8;
typedef __attribute__((ext_vector_type(4))) float f32x4;

// float -> bf16 (RNE) and back, as raw shorts
__device__ inline short f2bf(float f) {
  unsigned u = __float_as_uint(f);
  u = u + 0x7fff + ((u >> 16) & 1);
  return (short)(u >> 16);
}
__device__ inline float bf2f(short h) {
  return __uint_as_float(((unsigned)(unsigned short)h) << 16);
}

// order-preserving float<->uint transform (for atomicMax on floats)
__device__ inline unsigned fenc(float f) {
  int b = __float_as_int(f);
  return (b < 0) ? ~(unsigned)b : ((unsigned)b | 0x80000000u);
}
__device__ inline float fdec(unsigned u) {
  int b = (u & 0x80000000u) ? (int)(u & 0x7fffffffu) : (int)~u;
  return __int_as_float(b);
}

// ---------------- degree count ----------------
__global__ __launch_bounds__(256) void k_count(const int* __restrict__ dst,
                                               int* __restrict__ cnt, int E) {
  int i = blockIdx.x * 256 + threadIdx.x;
  if (i < E) atomicAdd(&cnt[dst[i]], 1);
}

// ---------------- hierarchical scan ----------------
__global__ __launch_bounds__(SB) void k_scan1(const int* __restrict__ cnt,
                                              float* __restrict__ dinv,
                                              int* __restrict__ bsum, int N) {
  __shared__ int red[SB];
  int t = threadIdx.x;
  int i = blockIdx.x * SB + t;
  int v = (i < N) ? cnt[i] : 0;
  if (i < N) dinv[i] = rsqrtf(1.0f + (float)v);
  red[t] = v;
  __syncthreads();
  for (int o = SB / 2; o; o >>= 1) {
    if (t < o) red[t] += red[t + o];
    __syncthreads();
  }
  if (t == 0) bsum[blockIdx.x] = red[0];
}

__global__ __launch_bounds__(256) void k_scan2(const int* __restrict__ bsum,
                                               int* __restrict__ boff, int nb,
                                               int* __restrict__ total_out) {
  __shared__ int s[256];
  int t = threadIdx.x;
  int v = (t < nb) ? bsum[t] : 0;
  s[t] = v;
  __syncthreads();
  for (int o = 1; o < 256; o <<= 1) {
    int u = (t >= o) ? s[t - o] : 0;
    __syncthreads();
    s[t] += u;
    __syncthreads();
  }
  boff[t] = s[t] - v;  // exclusive
  if (t == 255) *total_out = s[255];
}

__global__ __launch_bounds__(SB) void k_scan3(const int* __restrict__ cnt,
                                              const int* __restrict__ boff,
                                              int* __restrict__ rowstart,
                                              int* __restrict__ cursor, int N) {
  __shared__ int s[SB];
  int t = threadIdx.x;
  int i = blockIdx.x * SB + t;
  int v = (i < N) ? cnt[i] : 0;
  s[t] = v;
  __syncthreads();
  for (int o = 1; o < SB; o <<= 1) {
    int u = (t >= o) ? s[t - o] : 0;
    __syncthreads();
    s[t] += u;
    __syncthreads();
  }
  int excl = s[t] - v + boff[blockIdx.x];
  if (i < N) {
    rowstart[i] = excl;
    cursor[i] = excl;
  }
}

__global__ __launch_bounds__(256) void k_fill(const int* __restrict__ src,
                                              const int* __restrict__ dst,
                                              int* __restrict__ cursor,
                                              int* __restrict__ eidx, int E) {
  int i = blockIdx.x * 256 + threadIdx.x;
  if (i < E) {
    int pos = atomicAdd(&cursor[dst[i]], 1);
    eidx[pos] = src[i];
  }
}

// ---------------- weight prep: transpose + split into bf16 hi/lo ----------------
__global__ __launch_bounds__(256) void k_wsplit(const float* __restrict__ W1,
                                                const float* __restrict__ W2,
                                                const float* __restrict__ W3,
                                                const float* __restrict__ Wg1,
                                                short* __restrict__ wt) {
  int i = blockIdx.x * 256 + threadIdx.x;
  const float* W;
  short *hi, *lo;
  int K, M, idx;
  if (i < 16384) {
    W = W1; hi = wt; lo = wt + 16384; K = 128; M = 128; idx = i;
  } else if (i < 32768) {
    W = W2; hi = wt + 32768; lo = wt + 49152; K = 128; M = 128; idx = i - 16384;
  } else if (i < 40960) {
    W = W3; hi = wt + 65536; lo = wt + 73728; K = 128; M = 64; idx = i - 32768;
  } else {
    W = Wg1; hi = wt + 81920; lo = wt + 90112; K = 64; M = 128; idx = i - 40960;
  }
  int k = idx / M, n = idx % M;
  float w = W[idx];
  short h = f2bf(w);
  hi[n * K + k] = h;
  lo[n * K + k] = f2bf(w - bf2f(h));
}

// ---------------- BN prep ----------------
__global__ __launch_bounds__(256) void k_bnprep(
    const float* __restrict__ g1, const float* __restrict__ b1,
    const float* __restrict__ m1, const float* __restrict__ v1,
    const float* __restrict__ g2, const float* __restrict__ b2,
    const float* __restrict__ m2, const float* __restrict__ v2,
    float* __restrict__ s1, float* __restrict__ h1, float* __restrict__ s2,
    float* __restrict__ h2) {
  int i = threadIdx.x;
  if (i < 128) {
    float s = g1[i] * rsqrtf(v1[i] + BN_EPS);
    s1[i] = s;
    h1[i] = b1[i] - m1[i] * s;
  } else {
    int j = i - 128;
    float s = g2[j] * rsqrtf(v2[j] + BN_EPS);
    s2[j] = s;
    h2[j] = b2[j] - m2[j] * s;
  }
}

// ---------------- MFMA split-bf16 GEMM ----------------
template <int K, int M, int BN, int DINV, int GATE>
__global__ __launch_bounds__(256, 4) void k_mgemm(
    const float* __restrict__ X, const short* __restrict__ Wthi,
    const short* __restrict__ Wtlo, const float* __restrict__ bns,
    const float* __restrict__ bnh, const float* __restrict__ dinv,
    const float* __restrict__ gbias, const float* __restrict__ Wg2v,
    const float* __restrict__ bg2v, float* __restrict__ Y,
    float* __restrict__ gate, int nrows) {
  constexpr int NC = K / 32;  // k chunks of 32
  constexpr int CT = M / 16;  // 16-col tiles
  const int lane = threadIdx.x & 63;
  const int wave = threadIdx.x >> 6;
  const int m16 = lane & 15;
  const int quad = lane >> 4;
  const int rowbase = blockIdx.x * 64 + wave * 16;
  const int arow = rowbase + m16;
  const bool rok = arow < nrows;

  bf16x8 ahi[NC], alo[NC];
#pragma unroll
  for (int c = 0; c < NC; ++c) {
    const int k0 = c * 32 + quad * 8;
    float4 v0 = make_float4(0.f, 0.f, 0.f, 0.f), v1 = v0;
    if (rok) {
      v0 = *(const float4*)(X + (size_t)arow * K + k0);
      v1 = *(const float4*)(X + (size_t)arow * K + k0 + 4);
    }
    float vv[8] = {v0.x, v0.y, v0.z, v0.w, v1.x, v1.y, v1.z, v1.w};
    if constexpr (BN) {
#pragma unroll
      for (int j = 0; j < 8; ++j)
        vv[j] = fmaxf(vv[j] * bns[k0 + j] + bnh[k0 + j], 0.f);
    }
#pragma unroll
    for (int j = 0; j < 8; ++j) {
      short h = f2bf(vv[j]);
      ahi[c][j] = h;
      alo[c][j] = f2bf(vv[j] - bf2f(h));
    }
  }

  float gp[4] = {0.f, 0.f, 0.f, 0.f};
#pragma unroll
  for (int ct = 0; ct < CT; ++ct) {
    f32x4 acc = {0.f, 0.f, 0.f, 0.f};
    const size_t wrow = (size_t)(ct * 16 + m16) * K + quad * 8;
#pragma unroll
    for (int c = 0; c < NC; ++c) {
      bf16x8 bhi = *(const bf16x8*)(Wthi + wrow + c * 32);
      bf16x8 blo = *(const bf16x8*)(Wtlo + wrow + c * 32);
      acc = __builtin_amdgcn_mfma_f32_16x16x32_bf16(ahi[c], bhi, acc, 0, 0, 0);
      acc = __builtin_amdgcn_mfma_f32_16x16x32_bf16(ahi[c], blo, acc, 0, 0, 0);
      acc = __builtin_amdgcn_mfma_f32_16x16x32_bf16(alo[c], bhi, acc, 0, 0, 0);
    }
    if constexpr (GATE) {
      const int col = ct * 16 + m16;
      const float gb = gbias[col], wg = Wg2v[col];
#pragma unroll
      for (int r = 0; r < 4; ++r) gp[r] += fmaxf(acc[r] + gb, 0.f) * wg;
    } else {
#pragma unroll
      for (int r = 0; r < 4; ++r) {
        const int row = rowbase + quad * 4 + r;
        if (row < nrows) {
          float v = acc[r];
          if constexpr (DINV) v *= dinv[row];
          Y[(size_t)row * M + ct * 16 + m16] = v;
        }
      }
    }
  }
  if constexpr (GATE) {
#pragma unroll
    for (int o = 1; o < 16; o <<= 1) {
#pragma unroll
      for (int r = 0; r < 4; ++r) gp[r] += __shfl_xor(gp[r], o, 64);
    }
    if (m16 == 0) {
      const float b2 = bg2v[0];
#pragma unroll
      for (int r = 0; r < 4; ++r) {
        const int row = rowbase + quad * 4 + r;
        if (row < nrows) gate[row] = gp[r] + b2;
      }
    }
  }
}

// ---------------- GCN aggregation (gather over CSR by dst) ----------------
template <int M>
__global__ __launch_bounds__(256) void k_agg(const float* __restrict__ hp,
                                             const int* __restrict__ rowstart,
                                             const int* __restrict__ eidx,
                                             const float* __restrict__ dinv,
                                             const float* __restrict__ bias,
                                             float* __restrict__ out, int N) {
  int w = (blockIdx.x * 256 + threadIdx.x) >> 6;  // wave = node
  int l = threadIdx.x & 63;
  if (w >= N) return;
  float di = dinv[w];
  int lo = rowstart[w], hi = rowstart[w + 1];
  if constexpr (M == 128) {
    float2 acc = ((const float2*)(hp + (size_t)w * 128))[l];  // self term
    float2 bb = ((const float2*)bias)[l];
    int e = lo;
    for (; e + 4 <= hi; e += 4) {
      int s0 = eidx[e + 0], s1 = eidx[e + 1], s2 = eidx[e + 2], s3 = eidx[e + 3];
      float2 v0 = ((const float2*)(hp + (size_t)s0 * 128))[l];
      float2 v1 = ((const float2*)(hp + (size_t)s1 * 128))[l];
      float2 v2 = ((const float2*)(hp + (size_t)s2 * 128))[l];
      float2 v3 = ((const float2*)(hp + (size_t)s3 * 128))[l];
      acc.x += (v0.x + v1.x) + (v2.x + v3.x);
      acc.y += (v0.y + v1.y) + (v2.y + v3.y);
    }
    for (; e < hi; ++e) {
      int s = eidx[e];
      float2 v = ((const float2*)(hp + (size_t)s * 128))[l];
      acc.x += v.x;
      acc.y += v.y;
    }
    acc.x = acc.x * di + bb.x;
    acc.y = acc.y * di + bb.y;
    ((float2*)(out + (size_t)w * 128))[l] = acc;
  } else {
    float acc = hp[(size_t)w * 64 + l];
    float bb = bias[l];
    int e = lo;
    for (; e + 4 <= hi; e += 4) {
      int s0 = eidx[e + 0], s1 = eidx[e + 1], s2 = eidx[e + 2], s3 = eidx[e + 3];
      float v0 = hp[(size_t)s0 * 64 + l];
      float v1 = hp[(size_t)s1 * 64 + l];
      float v2 = hp[(size_t)s2 * 64 + l];
      float v3 = hp[(size_t)s3 * 64 + l];
      acc += (v0 + v1) + (v2 + v3);
    }
    for (; e < hi; ++e) acc += hp[(size_t)eidx[e] * 64 + l];
    out[(size_t)w * 64 + l] = acc * di + bb;
  }
}

// ---------------- pooling, parallel decomposition ----------------
__global__ __launch_bounds__(128) void k_gbounds(const int* __restrict__ batch,
                                                 int* __restrict__ gstart,
                                                 int N) {
  int g = threadIdx.x;
  if (g > GG) return;
  int lo = 0, hi = N;
  while (lo < hi) {
    int mid = (lo + hi) >> 1;
    if (batch[mid] < g) lo = mid + 1;
    else hi = mid;
  }
  gstart[g] = lo;
}

__global__ __launch_bounds__(256) void k_pmax(const float* __restrict__ gate,
                                              const int* __restrict__ batch,
                                              unsigned* __restrict__ gmaxu,
                                              int N) {
  int i = blockIdx.x * 256 + threadIdx.x;
  if (i < N) atomicMax(&gmaxu[batch[i]], fenc(gate[i]));
}

// grid = GG*CPB blocks, 256 thr (4 waves). lane=feature, wave strides nodes.
__global__ __launch_bounds__(256) void k_psum(const float* __restrict__ gate,
                                              const float* __restrict__ h3,
                                              const unsigned* __restrict__ gmaxu,
                                              const int* __restrict__ gstart,
                                              float* __restrict__ pooledw,
                                              float* __restrict__ ssum) {
  __shared__ float accs[4][64];
  __shared__ float ses[4];
  const int g = blockIdx.x / CPB;
  const int c = blockIdx.x % CPB;
  const int lo = gstart[g], hi = gstart[g + 1];
  const int len = hi - lo;
  const int b0 = lo + (int)(((long long)len * c) / CPB);
  const int b1 = lo + (int)(((long long)len * (c + 1)) / CPB);
  const int wave = threadIdx.x >> 6, lane = threadIdx.x & 63;
  const float m = fdec(gmaxu[g]);
  float acc = 0.f, se = 0.f;
  for (int i = b0 + wave; i < b1; i += 4) {
    float e = expf(gate[i] - m);
    acc += e * h3[(size_t)i * 64 + lane];
    se += e;
  }
  accs[wave][lane] = acc;
  if (lane == 0) ses[wave] = se;
  __syncthreads();
  if (threadIdx.x < 64) {
    float a = accs[0][threadIdx.x] + accs[1][threadIdx.x] +
              accs[2][threadIdx.x] + accs[3][threadIdx.x];
    if (a != 0.f) atomicAdd(&pooledw[g * 64 + threadIdx.x], a);
  }
  if (threadIdx.x == 64) {
    float s = ses[0] + ses[1] + ses[2] + ses[3];
    if (s != 0.f) atomicAdd(&ssum[g], s);
  }
}

// ---------------- head MLP (single block); normalization fused into P load --
__global__ __launch_bounds__(256) void k_head(const float* __restrict__ pooledw,
                                              const float* __restrict__ ssum,
                                              const float* __restrict__ Wm1,
                                              const float* __restrict__ bm1,
                                              const float* __restrict__ Wm2,
                                              const float* __restrict__ bm2,
                                              float* __restrict__ out) {
  __shared__ float P[64 * 64];
  __shared__ float T[64 * 128];
  int tid = threadIdx.x;
  for (int i = tid; i < 4096; i += 256) {
    float s = ssum[i >> 6];
    P[i] = pooledw[i] * ((s > 0.f) ? 1.0f / s : 0.f);
  }
  __syncthreads();
  for (int e = tid; e < 8192; e += 256) {
    int r = e >> 7, c = e & 127;
    float a = bm1[c];
    for (int k = 0; k < 64; ++k) a += P[r * 64 + k] * Wm1[k * 128 + c];
    T[e] = fmaxf(a, 0.f);
  }
  __syncthreads();
  for (int e = tid; e < 4096; e += 256) {
    int r = e >> 6, c = e & 63;
    float a = bm2[c];
    for (int k = 0; k < 128; ++k) a += T[r * 128 + k] * Wm2[k * 64 + c];
    out[e] = a;
  }
}

extern "C" void kernel_launch(void* const* d_in, const int* in_sizes, int n_in,
                              void* d_out, int out_size, void* d_ws,
                              size_t ws_size, hipStream_t stream) {
  const int N = NN, E = EE;
  const float* x = (const float*)d_in[0];
  const int* ei = (const int*)d_in[1];
  const int* batch = (const int*)d_in[2];
  const float* W1 = (const float*)d_in[3];
  const float* b1 = (const float*)d_in[4];
  const float* W2 = (const float*)d_in[5];
  const float* b2 = (const float*)d_in[6];
  const float* W3 = (const float*)d_in[7];
  const float* b3 = (const float*)d_in[8];
  const float* g1 = (const float*)d_in[9];
  const float* beta1 = (const float*)d_in[10];
  const float* g2 = (const float*)d_in[11];
  const float* beta2 = (const float*)d_in[12];
  const float* mean1 = (const float*)d_in[13];
  const float* var1 = (const float*)d_in[14];
  const float* mean2 = (const float*)d_in[15];
  const float* var2 = (const float*)d_in[16];
  const float* Wg1 = (const float*)d_in[17];
  const float* bg1 = (const float*)d_in[18];
  const float* Wg2 = (const float*)d_in[19];
  const float* bg2 = (const float*)d_in[20];
  const float* Wm1 = (const float*)d_in[21];
  const float* bm1 = (const float*)d_in[22];
  const float* Wm2 = (const float*)d_in[23];
  const float* bm2 = (const float*)d_in[24];
  float* out = (float*)d_out;

  const int* src = ei;
  const int* dst = ei + E;

  char* wsb = (char*)d_ws;
  size_t off = 0;
  auto alloc = [&](size_t elems) -> void* {
    void* p = wsb + off;
    off += elems * 4;
    return p;
  };
  int* cnt = (int*)alloc(N);
  int* rowstart = (int*)alloc(N + 4);
  int* cursor = (int*)alloc(N);
  int* eidx = (int*)alloc(E);
  float* dinv = (float*)alloc(N);
  float* gate = (float*)alloc(N);
  float* bufA = (float*)alloc((size_t)N * 128);
  float* bufB = (float*)alloc((size_t)N * 128);
  int* bsum = (int*)alloc(256);
  int* boff = (int*)alloc(256);
  short* wt = (short*)alloc(49152);  // 98304 shorts
  float* bn1s = (float*)alloc(128);
  float* bn1h = (float*)alloc(128);
  float* bn2s = (float*)alloc(128);
  float* bn2h = (float*)alloc(128);
  // pooling buffers (contiguous for one memset): pooledw + ssum + gmaxu + gstart
  float* pooledw = (float*)alloc(GG * 64);
  float* ssum = (float*)alloc(GG);
  unsigned* gmaxu = (unsigned*)alloc(GG);
  int* gstart = (int*)alloc(GG + 4);
  (void)ws_size;
  (void)n_in;
  (void)in_sizes;
  (void)out_size;

  const int nscan = (N + SB - 1) / SB;

  // CSR build (once, reused for all 3 conv layers)
  hipMemsetAsync(cnt, 0, N * sizeof(int), stream);
  hipMemsetAsync(pooledw, 0, (GG * 64 + GG + GG) * sizeof(float), stream);
  k_count<<<(E + 255) / 256, 256, 0, stream>>>(dst, cnt, E);
  k_scan1<<<nscan, SB, 0, stream>>>(cnt, dinv, bsum, N);
  k_scan2<<<1, 256, 0, stream>>>(bsum, boff, nscan, rowstart + N);
  k_scan3<<<nscan, SB, 0, stream>>>(cnt, boff, rowstart, cursor, N);
  k_fill<<<(E + 255) / 256, 256, 0, stream>>>(src, dst, cursor, eidx, E);

  // weight/bn prep + graph bounds
  k_wsplit<<<192, 256, 0, stream>>>(W1, W2, W3, Wg1, wt);
  k_bnprep<<<1, 256, 0, stream>>>(g1, beta1, mean1, var1, g2, beta2, mean2,
                                  var2, bn1s, bn1h, bn2s, bn2h);
  k_gbounds<<<1, 128, 0, stream>>>(batch, gstart, N);

  const int gb = (N + 63) / 64;         // GEMM blocks (64 rows each)
  const int ab = (N * 64 + 255) / 256;  // agg blocks (wave per node)

  // Layer 1: h1' = (x@W1)*dinv ; agg
  k_mgemm<128, 128, 0, 1, 0><<<gb, 256, 0, stream>>>(
      x, wt, wt + 16384, nullptr, nullptr, dinv, nullptr, nullptr, nullptr,
      bufA, nullptr, N);
  k_agg<128><<<ab, 256, 0, stream>>>(bufA, rowstart, eidx, dinv, b1, bufB, N);

  // Layer 2 (BN1+relu fused into A load)
  k_mgemm<128, 128, 1, 1, 0><<<gb, 256, 0, stream>>>(
      bufB, wt + 32768, wt + 49152, bn1s, bn1h, dinv, nullptr, nullptr,
      nullptr, bufA, nullptr, N);
  k_agg<128><<<ab, 256, 0, stream>>>(bufA, rowstart, eidx, dinv, b2, bufB, N);

  // Layer 3 (M=64, BN2 fused)
  k_mgemm<128, 64, 1, 1, 0><<<gb, 256, 0, stream>>>(
      bufB, wt + 65536, wt + 73728, bn2s, bn2h, dinv, nullptr, nullptr,
      nullptr, bufA, nullptr, N);
  k_agg<64><<<ab, 256, 0, stream>>>(bufA, rowstart, eidx, dinv, b3, bufB, N);
  // h3 = bufB (N x 64)

  // gate = relu(h3@Wg1+bg1)@Wg2+bg2 (fused epilogue)
  k_mgemm<64, 128, 0, 0, 1><<<gb, 256, 0, stream>>>(
      bufB, wt + 81920, wt + 90112, nullptr, nullptr, nullptr, bg1, Wg2, bg2,
      nullptr, gate, N);

  // softmax pooling (parallel): max -> exp-sums -> (normalize in head)
  k_pmax<<<(N + 255) / 256, 256, 0, stream>>>(gate, batch, gmaxu, N);
  k_psum<<<GG * CPB, 256, 0, stream>>>(gate, bufB, gmaxu, gstart, pooledw,
                                       ssum);

  // head MLP
  k_head<<<1, 256, 0, stream>>>(pooledw, ssum, Wm1, bm1, Wm2, bm2, out);
}

// Round 6
// 774.995 us; speedup vs baseline: 1.5216x; 1.5216x over previous
//
#include <hip/hip_runtime.h>
#include <hip/hip_bf16.h>
#include <math.h>

#define NN 100000
#define EE 1000000
#define GG 64
#define BN_EPS 1e-5f
#define SB 512  // scan block size
#define CPB 16  // pooling chunks per graph

typedef __attribute__((ext_vector_type(8))) short bf16x8;
typedef __attribute__((ext_vector_type(4))) float f32x4;

// float -> bf16 (RNE) and back, as raw shorts
__device__ inline short f2bf(float f) {
  unsigned u = __float_as_uint(f);
  u = u + 0x7fff + ((u >> 16) & 1);
  return (short)(u >> 16);
}
__device__ inline float bf2f(short h) {
  return __uint_as_float(((unsigned)(unsigned short)h) << 16);
}

// order-preserving float<->uint transform (for atomicMax on floats)
// all encodings are >= 0x007FFFFF, so 0 is a safe identity for max
__device__ inline unsigned fenc(float f) {
  int b = __float_as_int(f);
  return (b < 0) ? ~(unsigned)b : ((unsigned)b | 0x80000000u);
}
__device__ inline float fdec(unsigned u) {
  int b = (u & 0x80000000u) ? (int)(u & 0x7fffffffu) : (int)~u;
  return __int_as_float(b);
}

// ---------------- degree count ----------------
__global__ __launch_bounds__(256) void k_count(const int* __restrict__ dst,
                                               int* __restrict__ cnt, int E) {
  int i = blockIdx.x * 256 + threadIdx.x;
  if (i < E) atomicAdd(&cnt[dst[i]], 1);
}

// ---------------- hierarchical scan ----------------
__global__ __launch_bounds__(SB) void k_scan1(const int* __restrict__ cnt,
                                              float* __restrict__ dinv,
                                              int* __restrict__ bsum, int N) {
  __shared__ int red[SB];
  int t = threadIdx.x;
  int i = blockIdx.x * SB + t;
  int v = (i < N) ? cnt[i] : 0;
  if (i < N) dinv[i] = rsqrtf(1.0f + (float)v);
  red[t] = v;
  __syncthreads();
  for (int o = SB / 2; o; o >>= 1) {
    if (t < o) red[t] += red[t + o];
    __syncthreads();
  }
  if (t == 0) bsum[blockIdx.x] = red[0];
}

__global__ __launch_bounds__(256) void k_scan2(const int* __restrict__ bsum,
                                               int* __restrict__ boff, int nb,
                                               int* __restrict__ total_out) {
  __shared__ int s[256];
  int t = threadIdx.x;
  int v = (t < nb) ? bsum[t] : 0;
  s[t] = v;
  __syncthreads();
  for (int o = 1; o < 256; o <<= 1) {
    int u = (t >= o) ? s[t - o] : 0;
    __syncthreads();
    s[t] += u;
    __syncthreads();
  }
  boff[t] = s[t] - v;  // exclusive
  if (t == 255) *total_out = s[255];
}

__global__ __launch_bounds__(SB) void k_scan3(const int* __restrict__ cnt,
                                              const int* __restrict__ boff,
                                              int* __restrict__ rowstart,
                                              int* __restrict__ cursor, int N) {
  __shared__ int s[SB];
  int t = threadIdx.x;
  int i = blockIdx.x * SB + t;
  int v = (i < N) ? cnt[i] : 0;
  s[t] = v;
  __syncthreads();
  for (int o = 1; o < SB; o <<= 1) {
    int u = (t >= o) ? s[t - o] : 0;
    __syncthreads();
    s[t] += u;
    __syncthreads();
  }
  int excl = s[t] - v + boff[blockIdx.x];
  if (i < N) {
    rowstart[i] = excl;
    cursor[i] = excl;
  }
}

__global__ __launch_bounds__(256) void k_fill(const int* __restrict__ src,
                                              const int* __restrict__ dst,
                                              int* __restrict__ cursor,
                                              int* __restrict__ eidx, int E) {
  int i = blockIdx.x * 256 + threadIdx.x;
  if (i < E) {
    int pos = atomicAdd(&cursor[dst[i]], 1);
    eidx[pos] = src[i];
  }
}

// ---------------- weight prep: transpose + split into bf16 hi/lo ----------------
__global__ __launch_bounds__(256) void k_wsplit(const float* __restrict__ W1,
                                                const float* __restrict__ W2,
                                                const float* __restrict__ W3,
                                                const float* __restrict__ Wg1,
                                                short* __restrict__ wt) {
  int i = blockIdx.x * 256 + threadIdx.x;
  const float* W;
  short *hi, *lo;
  int K, M, idx;
  if (i < 16384) {
    W = W1; hi = wt; lo = wt + 16384; K = 128; M = 128; idx = i;
  } else if (i < 32768) {
    W = W2; hi = wt + 32768; lo = wt + 49152; K = 128; M = 128; idx = i - 16384;
  } else if (i < 40960) {
    W = W3; hi = wt + 65536; lo = wt + 73728; K = 128; M = 64; idx = i - 32768;
  } else {
    W = Wg1; hi = wt + 81920; lo = wt + 90112; K = 64; M = 128; idx = i - 40960;
  }
  int k = idx / M, n = idx % M;
  float w = W[idx];
  short h = f2bf(w);
  hi[n * K + k] = h;
  lo[n * K + k] = f2bf(w - bf2f(h));
}

// ---------------- BN prep ----------------
__global__ __launch_bounds__(256) void k_bnprep(
    const float* __restrict__ g1, const float* __restrict__ b1,
    const float* __restrict__ m1, const float* __restrict__ v1,
    const float* __restrict__ g2, const float* __restrict__ b2,
    const float* __restrict__ m2, const float* __restrict__ v2,
    float* __restrict__ s1, float* __restrict__ h1, float* __restrict__ s2,
    float* __restrict__ h2) {
  int i = threadIdx.x;
  if (i < 128) {
    float s = g1[i] * rsqrtf(v1[i] + BN_EPS);
    s1[i] = s;
    h1[i] = b1[i] - m1[i] * s;
  } else {
    int j = i - 128;
    float s = g2[j] * rsqrtf(v2[j] + BN_EPS);
    s2[j] = s;
    h2[j] = b2[j] - m2[j] * s;
  }
}

// ---------------- MFMA split-bf16 GEMM ----------------
template <int K, int M, int BN, int DINV, int GATE>
__global__ __launch_bounds__(256, 4) void k_mgemm(
    const float* __restrict__ X, const short* __restrict__ Wthi,
    const short* __restrict__ Wtlo, const float* __restrict__ bns,
    const float* __restrict__ bnh, const float* __restrict__ dinv,
    const float* __restrict__ gbias, const float* __restrict__ Wg2v,
    const float* __restrict__ bg2v, float* __restrict__ Y,
    float* __restrict__ gate, int nrows) {
  constexpr int NC = K / 32;  // k chunks of 32
  constexpr int CT = M / 16;  // 16-col tiles
  const int lane = threadIdx.x & 63;
  const int wave = threadIdx.x >> 6;
  const int m16 = lane & 15;
  const int quad = lane >> 4;
  const int rowbase = blockIdx.x * 64 + wave * 16;
  const int arow = rowbase + m16;
  const bool rok = arow < nrows;

  bf16x8 ahi[NC], alo[NC];
#pragma unroll
  for (int c = 0; c < NC; ++c) {
    const int k0 = c * 32 + quad * 8;
    float4 v0 = make_float4(0.f, 0.f, 0.f, 0.f), v1 = v0;
    if (rok) {
      v0 = *(const float4*)(X + (size_t)arow * K + k0);
      v1 = *(const float4*)(X + (size_t)arow * K + k0 + 4);
    }
    float vv[8] = {v0.x, v0.y, v0.z, v0.w, v1.x, v1.y, v1.z, v1.w};
    if constexpr (BN) {
#pragma unroll
      for (int j = 0; j < 8; ++j)
        vv[j] = fmaxf(vv[j] * bns[k0 + j] + bnh[k0 + j], 0.f);
    }
#pragma unroll
    for (int j = 0; j < 8; ++j) {
      short h = f2bf(vv[j]);
      ahi[c][j] = h;
      alo[c][j] = f2bf(vv[j] - bf2f(h));
    }
  }

  float gp[4] = {0.f, 0.f, 0.f, 0.f};
#pragma unroll
  for (int ct = 0; ct < CT; ++ct) {
    f32x4 acc = {0.f, 0.f, 0.f, 0.f};
    const size_t wrow = (size_t)(ct * 16 + m16) * K + quad * 8;
#pragma unroll
    for (int c = 0; c < NC; ++c) {
      bf16x8 bhi = *(const bf16x8*)(Wthi + wrow + c * 32);
      bf16x8 blo = *(const bf16x8*)(Wtlo + wrow + c * 32);
      acc = __builtin_amdgcn_mfma_f32_16x16x32_bf16(ahi[c], bhi, acc, 0, 0, 0);
      acc = __builtin_amdgcn_mfma_f32_16x16x32_bf16(ahi[c], blo, acc, 0, 0, 0);
      acc = __builtin_amdgcn_mfma_f32_16x16x32_bf16(alo[c], bhi, acc, 0, 0, 0);
    }
    if constexpr (GATE) {
      const int col = ct * 16 + m16;
      const float gb = gbias[col], wg = Wg2v[col];
#pragma unroll
      for (int r = 0; r < 4; ++r) gp[r] += fmaxf(acc[r] + gb, 0.f) * wg;
    } else {
#pragma unroll
      for (int r = 0; r < 4; ++r) {
        const int row = rowbase + quad * 4 + r;
        if (row < nrows) {
          float v = acc[r];
          if constexpr (DINV) v *= dinv[row];
          Y[(size_t)row * M + ct * 16 + m16] = v;
        }
      }
    }
  }
  if constexpr (GATE) {
#pragma unroll
    for (int o = 1; o < 16; o <<= 1) {
#pragma unroll
      for (int r = 0; r < 4; ++r) gp[r] += __shfl_xor(gp[r], o, 64);
    }
    if (m16 == 0) {
      const float b2 = bg2v[0];
#pragma unroll
      for (int r = 0; r < 4; ++r) {
        const int row = rowbase + quad * 4 + r;
        if (row < nrows) gate[row] = gp[r] + b2;
      }
    }
  }
}

// ---------------- GCN aggregation (gather over CSR by dst) ----------------
template <int M>
__global__ __launch_bounds__(256) void k_agg(const float* __restrict__ hp,
                                             const int* __restrict__ rowstart,
                                             const int* __restrict__ eidx,
                                             const float* __restrict__ dinv,
                                             const float* __restrict__ bias,
                                             float* __restrict__ out, int N) {
  int w = (blockIdx.x * 256 + threadIdx.x) >> 6;  // wave = node
  int l = threadIdx.x & 63;
  if (w >= N) return;
  float di = dinv[w];
  int lo = rowstart[w], hi = rowstart[w + 1];
  if constexpr (M == 128) {
    float2 acc = ((const float2*)(hp + (size_t)w * 128))[l];  // self term
    float2 bb = ((const float2*)bias)[l];
    int e = lo;
    for (; e + 4 <= hi; e += 4) {
      int s0 = eidx[e + 0], s1 = eidx[e + 1], s2 = eidx[e + 2], s3 = eidx[e + 3];
      float2 v0 = ((const float2*)(hp + (size_t)s0 * 128))[l];
      float2 v1 = ((const float2*)(hp + (size_t)s1 * 128))[l];
      float2 v2 = ((const float2*)(hp + (size_t)s2 * 128))[l];
      float2 v3 = ((const float2*)(hp + (size_t)s3 * 128))[l];
      acc.x += (v0.x + v1.x) + (v2.x + v3.x);
      acc.y += (v0.y + v1.y) + (v2.y + v3.y);
    }
    for (; e < hi; ++e) {
      int s = eidx[e];
      float2 v = ((const float2*)(hp + (size_t)s * 128))[l];
      acc.x += v.x;
      acc.y += v.y;
    }
    acc.x = acc.x * di + bb.x;
    acc.y = acc.y * di + bb.y;
    ((float2*)(out + (size_t)w * 128))[l] = acc;
  } else {
    float acc = hp[(size_t)w * 64 + l];
    float bb = bias[l];
    int e = lo;
    for (; e + 4 <= hi; e += 4) {
      int s0 = eidx[e + 0], s1 = eidx[e + 1], s2 = eidx[e + 2], s3 = eidx[e + 3];
      float v0 = hp[(size_t)s0 * 64 + l];
      float v1 = hp[(size_t)s1 * 64 + l];
      float v2 = hp[(size_t)s2 * 64 + l];
      float v3 = hp[(size_t)s3 * 64 + l];
      acc += (v0 + v1) + (v2 + v3);
    }
    for (; e < hi; ++e) acc += hp[(size_t)eidx[e] * 64 + l];
    out[(size_t)w * 64 + l] = acc * di + bb;
  }
}

// ---------------- pooling, parallel decomposition ----------------
__global__ __launch_bounds__(128) void k_gbounds(const int* __restrict__ batch,
                                                 int* __restrict__ gstart,
                                                 int N) {
  int g = threadIdx.x;
  if (g > GG) return;
  int lo = 0, hi = N;
  while (lo < hi) {
    int mid = (lo + hi) >> 1;
    if (batch[mid] < g) lo = mid + 1;
    else hi = mid;
  }
  gstart[g] = lo;
}

// chunked max over contiguous per-graph ranges: ONE atomicMax per block
__global__ __launch_bounds__(256) void k_pmax(const float* __restrict__ gate,
                                              const int* __restrict__ gstart,
                                              unsigned* __restrict__ gmaxu) {
  __shared__ unsigned red[256];
  const int g = blockIdx.x / CPB;
  const int c = blockIdx.x % CPB;
  const int lo = gstart[g], hi = gstart[g + 1];
  const int len = hi - lo;
  const int b0 = lo + (int)(((long long)len * c) / CPB);
  const int b1 = lo + (int)(((long long)len * (c + 1)) / CPB);
  unsigned mx = 0u;
  for (int i = b0 + threadIdx.x; i < b1; i += 256) mx = max(mx, fenc(gate[i]));
  red[threadIdx.x] = mx;
  __syncthreads();
  for (int o = 128; o; o >>= 1) {
    if (threadIdx.x < o)
      red[threadIdx.x] = max(red[threadIdx.x], red[threadIdx.x + o]);
    __syncthreads();
  }
  if (threadIdx.x == 0 && red[0] != 0u) atomicMax(&gmaxu[g], red[0]);
}

// grid = GG*CPB blocks, 256 thr (4 waves). lane=feature, wave strides nodes.
__global__ __launch_bounds__(256) void k_psum(const float* __restrict__ gate,
                                              const float* __restrict__ h3,
                                              const unsigned* __restrict__ gmaxu,
                                              const int* __restrict__ gstart,
                                              float* __restrict__ pooledw,
                                              float* __restrict__ ssum) {
  __shared__ float accs[4][64];
  __shared__ float ses[4];
  const int g = blockIdx.x / CPB;
  const int c = blockIdx.x % CPB;
  const int lo = gstart[g], hi = gstart[g + 1];
  const int len = hi - lo;
  const int b0 = lo + (int)(((long long)len * c) / CPB);
  const int b1 = lo + (int)(((long long)len * (c + 1)) / CPB);
  const int wave = threadIdx.x >> 6, lane = threadIdx.x & 63;
  const float m = fdec(gmaxu[g]);
  float acc = 0.f, se = 0.f;
  for (int i = b0 + wave; i < b1; i += 4) {
    float e = expf(gate[i] - m);
    acc += e * h3[(size_t)i * 64 + lane];
    se += e;
  }
  accs[wave][lane] = acc;
  if (lane == 0) ses[wave] = se;
  __syncthreads();
  if (threadIdx.x < 64) {
    float a = accs[0][threadIdx.x] + accs[1][threadIdx.x] +
              accs[2][threadIdx.x] + accs[3][threadIdx.x];
    if (a != 0.f) atomicAdd(&pooledw[g * 64 + threadIdx.x], a);
  }
  if (threadIdx.x == 64) {
    float s = ses[0] + ses[1] + ses[2] + ses[3];
    if (s != 0.f) atomicAdd(&ssum[g], s);
  }
}

// ---------------- head MLP (single block); normalization fused into P load --
__global__ __launch_bounds__(256) void k_head(const float* __restrict__ pooledw,
                                              const float* __restrict__ ssum,
                                              const float* __restrict__ Wm1,
                                              const float* __restrict__ bm1,
                                              const float* __restrict__ Wm2,
                                              const float* __restrict__ bm2,
                                              float* __restrict__ out) {
  __shared__ float P[64 * 64];
  __shared__ float T[64 * 128];
  int tid = threadIdx.x;
  for (int i = tid; i < 4096; i += 256) {
    float s = ssum[i >> 6];
    P[i] = pooledw[i] * ((s > 0.f) ? 1.0f / s : 0.f);
  }
  __syncthreads();
  for (int e = tid; e < 8192; e += 256) {
    int r = e >> 7, c = e & 127;
    float a = bm1[c];
    for (int k = 0; k < 64; ++k) a += P[r * 64 + k] * Wm1[k * 128 + c];
    T[e] = fmaxf(a, 0.f);
  }
  __syncthreads();
  for (int e = tid; e < 4096; e += 256) {
    int r = e >> 6, c = e & 63;
    float a = bm2[c];
    for (int k = 0; k < 128; ++k) a += T[r * 128 + k] * Wm2[k * 64 + c];
    out[e] = a;
  }
}

extern "C" void kernel_launch(void* const* d_in, const int* in_sizes, int n_in,
                              void* d_out, int out_size, void* d_ws,
                              size_t ws_size, hipStream_t stream) {
  const int N = NN, E = EE;
  const float* x = (const float*)d_in[0];
  const int* ei = (const int*)d_in[1];
  const int* batch = (const int*)d_in[2];
  const float* W1 = (const float*)d_in[3];
  const float* b1 = (const float*)d_in[4];
  const float* W2 = (const float*)d_in[5];
  const float* b2 = (const float*)d_in[6];
  const float* W3 = (const float*)d_in[7];
  const float* b3 = (const float*)d_in[8];
  const float* g1 = (const float*)d_in[9];
  const float* beta1 = (const float*)d_in[10];
  const float* g2 = (const float*)d_in[11];
  const float* beta2 = (const float*)d_in[12];
  const float* mean1 = (const float*)d_in[13];
  const float* var1 = (const float*)d_in[14];
  const float* mean2 = (const float*)d_in[15];
  const float* var2 = (const float*)d_in[16];
  const float* Wg1 = (const float*)d_in[17];
  const float* bg1 = (const float*)d_in[18];
  const float* Wg2 = (const float*)d_in[19];
  const float* bg2 = (const float*)d_in[20];
  const float* Wm1 = (const float*)d_in[21];
  const float* bm1 = (const float*)d_in[22];
  const float* Wm2 = (const float*)d_in[23];
  const float* bm2 = (const float*)d_in[24];
  float* out = (float*)d_out;

  const int* src = ei;
  const int* dst = ei + E;

  char* wsb = (char*)d_ws;
  size_t off = 0;
  auto alloc = [&](size_t elems) -> void* {
    void* p = wsb + off;
    off += elems * 4;
    return p;
  };
  int* cnt = (int*)alloc(N);
  int* rowstart = (int*)alloc(N + 4);
  int* cursor = (int*)alloc(N);
  int* eidx = (int*)alloc(E);
  float* dinv = (float*)alloc(N);
  float* gate = (float*)alloc(N);
  float* bufA = (float*)alloc((size_t)N * 128);
  float* bufB = (float*)alloc((size_t)N * 128);
  int* bsum = (int*)alloc(256);
  int* boff = (int*)alloc(256);
  short* wt = (short*)alloc(49152);  // 98304 shorts
  float* bn1s = (float*)alloc(128);
  float* bn1h = (float*)alloc(128);
  float* bn2s = (float*)alloc(128);
  float* bn2h = (float*)alloc(128);
  // pooling buffers (contiguous for one memset): pooledw + ssum + gmaxu
  float* pooledw = (float*)alloc(GG * 64);
  float* ssum = (float*)alloc(GG);
  unsigned* gmaxu = (unsigned*)alloc(GG);
  int* gstart = (int*)alloc(GG + 4);
  (void)ws_size;
  (void)n_in;
  (void)in_sizes;
  (void)out_size;

  const int nscan = (N + SB - 1) / SB;

  // CSR build (once, reused for all 3 conv layers)
  hipMemsetAsync(cnt, 0, N * sizeof(int), stream);
  hipMemsetAsync(pooledw, 0, (GG * 64 + GG + GG) * sizeof(float), stream);
  k_count<<<(E + 255) / 256, 256, 0, stream>>>(dst, cnt, E);
  k_scan1<<<nscan, SB, 0, stream>>>(cnt, dinv, bsum, N);
  k_scan2<<<1, 256, 0, stream>>>(bsum, boff, nscan, rowstart + N);
  k_scan3<<<nscan, SB, 0, stream>>>(cnt, boff, rowstart, cursor, N);
  k_fill<<<(E + 255) / 256, 256, 0, stream>>>(src, dst, cursor, eidx, E);

  // weight/bn prep + graph bounds
  k_wsplit<<<192, 256, 0, stream>>>(W1, W2, W3, Wg1, wt);
  k_bnprep<<<1, 256, 0, stream>>>(g1, beta1, mean1, var1, g2, beta2, mean2,
                                  var2, bn1s, bn1h, bn2s, bn2h);
  k_gbounds<<<1, 128, 0, stream>>>(batch, gstart, N);

  const int gb = (N + 63) / 64;         // GEMM blocks (64 rows each)
  const int ab = (N * 64 + 255) / 256;  // agg blocks (wave per node)

  // Layer 1: h1' = (x@W1)*dinv ; agg
  k_mgemm<128, 128, 0, 1, 0><<<gb, 256, 0, stream>>>(
      x, wt, wt + 16384, nullptr, nullptr, dinv, nullptr, nullptr, nullptr,
      bufA, nullptr, N);
  k_agg<128><<<ab, 256, 0, stream>>>(bufA, rowstart, eidx, dinv, b1, bufB, N);

  // Layer 2 (BN1+relu fused into A load)
  k_mgemm<128, 128, 1, 1, 0><<<gb, 256, 0, stream>>>(
      bufB, wt + 32768, wt + 49152, bn1s, bn1h, dinv, nullptr, nullptr,
      nullptr, bufA, nullptr, N);
  k_agg<128><<<ab, 256, 0, stream>>>(bufA, rowstart, eidx, dinv, b2, bufB, N);

  // Layer 3 (M=64, BN2 fused)
  k_mgemm<128, 64, 1, 1, 0><<<gb, 256, 0, stream>>>(
      bufB, wt + 65536, wt + 73728, bn2s, bn2h, dinv, nullptr, nullptr,
      nullptr, bufA, nullptr, N);
  k_agg<64><<<ab, 256, 0, stream>>>(bufA, rowstart, eidx, dinv, b3, bufB, N);
  // h3 = bufB (N x 64)

  // gate = relu(h3@Wg1+bg1)@Wg2+bg2 (fused epilogue)
  k_mgemm<64, 128, 0, 0, 1><<<gb, 256, 0, stream>>>(
      bufB, wt + 81920, wt + 90112, nullptr, nullptr, nullptr, bg1, Wg2, bg2,
      nullptr, gate, N);

  // softmax pooling (parallel): chunked max -> exp-sums -> (normalize in head)
  k_pmax<<<GG * CPB, 256, 0, stream>>>(gate, gstart, gmaxu);
  k_psum<<<GG * CPB, 256, 0, stream>>>(gate, bufB, gmaxu, gstart, pooledw,
                                       ssum);

  // head MLP
  k_head<<<1, 256, 0, stream>>>(pooledw, ssum, Wm1, bm1, Wm2, bm2, out);
}

// Round 7
// 757.149 us; speedup vs baseline: 1.5575x; 1.0236x over previous
//
#include <hip/hip_runtime.h>
#include <hip/hip_bf16.h>
#include <math.h>

#define NN 100000
#define EE 1000000
#define GG 64
#define BN_EPS 1e-5f
#define SB 512  // scan block size
#define CPB 16  // pooling chunks per graph

typedef __attribute__((ext_vector_type(8))) short bf16x8;
typedef __attribute__((ext_vector_type(4))) float f32x4;

// float -> bf16 (RNE) and back, as raw shorts
__device__ inline short f2bf(float f) {
  unsigned u = __float_as_uint(f);
  u = u + 0x7fff + ((u >> 16) & 1);
  return (short)(u >> 16);
}
__device__ inline float bf2f(short h) {
  return __uint_as_float(((unsigned)(unsigned short)h) << 16);
}

// order-preserving float<->uint transform (for atomicMax on floats)
__device__ inline unsigned fenc(float f) {
  int b = __float_as_int(f);
  return (b < 0) ? ~(unsigned)b : ((unsigned)b | 0x80000000u);
}
__device__ inline float fdec(unsigned u) {
  int b = (u & 0x80000000u) ? (int)(u & 0x7fffffffu) : (int)~u;
  return __int_as_float(b);
}

// ---------------- degree count ----------------
__global__ __launch_bounds__(256) void k_count(const int* __restrict__ dst,
                                               int* __restrict__ cnt, int E) {
  int i = blockIdx.x * 256 + threadIdx.x;
  if (i < E) atomicAdd(&cnt[dst[i]], 1);
}

// ---------------- hierarchical scan ----------------
__global__ __launch_bounds__(SB) void k_scan1(const int* __restrict__ cnt,
                                              float* __restrict__ dinv,
                                              int* __restrict__ bsum, int N) {
  __shared__ int red[SB];
  int t = threadIdx.x;
  int i = blockIdx.x * SB + t;
  int v = (i < N) ? cnt[i] : 0;
  if (i < N) dinv[i] = rsqrtf(1.0f + (float)v);
  red[t] = v;
  __syncthreads();
  for (int o = SB / 2; o; o >>= 1) {
    if (t < o) red[t] += red[t + o];
    __syncthreads();
  }
  if (t == 0) bsum[blockIdx.x] = red[0];
}

__global__ __launch_bounds__(256) void k_scan2(const int* __restrict__ bsum,
                                               int* __restrict__ boff, int nb,
                                               int* __restrict__ total_out) {
  __shared__ int s[256];
  int t = threadIdx.x;
  int v = (t < nb) ? bsum[t] : 0;
  s[t] = v;
  __syncthreads();
  for (int o = 1; o < 256; o <<= 1) {
    int u = (t >= o) ? s[t - o] : 0;
    __syncthreads();
    s[t] += u;
    __syncthreads();
  }
  boff[t] = s[t] - v;  // exclusive
  if (t == 255) *total_out = s[255];
}

__global__ __launch_bounds__(SB) void k_scan3(const int* __restrict__ cnt,
                                              const int* __restrict__ boff,
                                              int* __restrict__ rowstart,
                                              int* __restrict__ cursor, int N) {
  __shared__ int s[SB];
  int t = threadIdx.x;
  int i = blockIdx.x * SB + t;
  int v = (i < N) ? cnt[i] : 0;
  s[t] = v;
  __syncthreads();
  for (int o = 1; o < SB; o <<= 1) {
    int u = (t >= o) ? s[t - o] : 0;
    __syncthreads();
    s[t] += u;
    __syncthreads();
  }
  int excl = s[t] - v + boff[blockIdx.x];
  if (i < N) {
    rowstart[i] = excl;
    cursor[i] = excl;
  }
}

__global__ __launch_bounds__(256) void k_fill(const int* __restrict__ src,
                                              const int* __restrict__ dst,
                                              int* __restrict__ cursor,
                                              int* __restrict__ eidx, int E) {
  int i = blockIdx.x * 256 + threadIdx.x;
  if (i < E) {
    int pos = atomicAdd(&cursor[dst[i]], 1);
    eidx[pos] = src[i];
  }
}

// ---------------- weight prep: transpose + split into bf16 hi/lo ----------------
__global__ __launch_bounds__(256) void k_wsplit(const float* __restrict__ W1,
                                                const float* __restrict__ W2,
                                                const float* __restrict__ W3,
                                                const float* __restrict__ Wg1,
                                                short* __restrict__ wt) {
  int i = blockIdx.x * 256 + threadIdx.x;
  const float* W;
  short *hi, *lo;
  int K, M, idx;
  if (i < 16384) {
    W = W1; hi = wt; lo = wt + 16384; K = 128; M = 128; idx = i;
  } else if (i < 32768) {
    W = W2; hi = wt + 32768; lo = wt + 49152; K = 128; M = 128; idx = i - 16384;
  } else if (i < 40960) {
    W = W3; hi = wt + 65536; lo = wt + 73728; K = 128; M = 64; idx = i - 32768;
  } else {
    W = Wg1; hi = wt + 81920; lo = wt + 90112; K = 64; M = 128; idx = i - 40960;
  }
  int k = idx / M, n = idx % M;
  float w = W[idx];
  short h = f2bf(w);
  hi[n * K + k] = h;
  lo[n * K + k] = f2bf(w - bf2f(h));
}

// ---------------- BN prep ----------------
__global__ __launch_bounds__(256) void k_bnprep(
    const float* __restrict__ g1, const float* __restrict__ b1,
    const float* __restrict__ m1, const float* __restrict__ v1,
    const float* __restrict__ g2, const float* __restrict__ b2,
    const float* __restrict__ m2, const float* __restrict__ v2,
    float* __restrict__ s1, float* __restrict__ h1, float* __restrict__ s2,
    float* __restrict__ h2) {
  int i = threadIdx.x;
  if (i < 128) {
    float s = g1[i] * rsqrtf(v1[i] + BN_EPS);
    s1[i] = s;
    h1[i] = b1[i] - m1[i] * s;
  } else {
    int j = i - 128;
    float s = g2[j] * rsqrtf(v2[j] + BN_EPS);
    s2[j] = s;
    h2[j] = b2[j] - m2[j] * s;
  }
}

// ---------------- MFMA split-bf16 GEMM ----------------
template <int K, int M, int BN, int DINV, int GATE>
__global__ __launch_bounds__(256, 4) void k_mgemm(
    const float* __restrict__ X, const short* __restrict__ Wthi,
    const short* __restrict__ Wtlo, const float* __restrict__ bns,
    const float* __restrict__ bnh, const float* __restrict__ dinv,
    const float* __restrict__ gbias, const float* __restrict__ Wg2v,
    const float* __restrict__ bg2v, float* __restrict__ Y,
    float* __restrict__ gate, int nrows) {
  constexpr int NC = K / 32;  // k chunks of 32
  constexpr int CT = M / 16;  // 16-col tiles
  const int lane = threadIdx.x & 63;
  const int wave = threadIdx.x >> 6;
  const int m16 = lane & 15;
  const int quad = lane >> 4;
  const int rowbase = blockIdx.x * 64 + wave * 16;
  const int arow = rowbase + m16;
  const bool rok = arow < nrows;

  bf16x8 ahi[NC], alo[NC];
#pragma unroll
  for (int c = 0; c < NC; ++c) {
    const int k0 = c * 32 + quad * 8;
    float4 v0 = make_float4(0.f, 0.f, 0.f, 0.f), v1 = v0;
    if (rok) {
      v0 = *(const float4*)(X + (size_t)arow * K + k0);
      v1 = *(const float4*)(X + (size_t)arow * K + k0 + 4);
    }
    float vv[8] = {v0.x, v0.y, v0.z, v0.w, v1.x, v1.y, v1.z, v1.w};
    if constexpr (BN) {
#pragma unroll
      for (int j = 0; j < 8; ++j)
        vv[j] = fmaxf(vv[j] * bns[k0 + j] + bnh[k0 + j], 0.f);
    }
#pragma unroll
    for (int j = 0; j < 8; ++j) {
      short h = f2bf(vv[j]);
      ahi[c][j] = h;
      alo[c][j] = f2bf(vv[j] - bf2f(h));
    }
  }

  float gp[4] = {0.f, 0.f, 0.f, 0.f};
#pragma unroll
  for (int ct = 0; ct < CT; ++ct) {
    f32x4 acc = {0.f, 0.f, 0.f, 0.f};
    const size_t wrow = (size_t)(ct * 16 + m16) * K + quad * 8;
#pragma unroll
    for (int c = 0; c < NC; ++c) {
      bf16x8 bhi = *(const bf16x8*)(Wthi + wrow + c * 32);
      bf16x8 blo = *(const bf16x8*)(Wtlo + wrow + c * 32);
      acc = __builtin_amdgcn_mfma_f32_16x16x32_bf16(ahi[c], bhi, acc, 0, 0, 0);
      acc = __builtin_amdgcn_mfma_f32_16x16x32_bf16(ahi[c], blo, acc, 0, 0, 0);
      acc = __builtin_amdgcn_mfma_f32_16x16x32_bf16(alo[c], bhi, acc, 0, 0, 0);
    }
    if constexpr (GATE) {
      const int col = ct * 16 + m16;
      const float gb = gbias[col], wg = Wg2v[col];
#pragma unroll
      for (int r = 0; r < 4; ++r) gp[r] += fmaxf(acc[r] + gb, 0.f) * wg;
    } else {
#pragma unroll
      for (int r = 0; r < 4; ++r) {
        const int row = rowbase + quad * 4 + r;
        if (row < nrows) {
          float v = acc[r];
          if constexpr (DINV) v *= dinv[row];
          Y[(size_t)row * M + ct * 16 + m16] = v;
        }
      }
    }
  }
  if constexpr (GATE) {
#pragma unroll
    for (int o = 1; o < 16; o <<= 1) {
#pragma unroll
      for (int r = 0; r < 4; ++r) gp[r] += __shfl_xor(gp[r], o, 64);
    }
    if (m16 == 0) {
      const float b2 = bg2v[0];
#pragma unroll
      for (int r = 0; r < 4; ++r) {
        const int row = rowbase + quad * 4 + r;
        if (row < nrows) gate[row] = gp[r] + b2;
      }
    }
  }
}

// ---------------- GCN aggregation (gather over CSR by dst) ----------------
// wave = node; two 32-lane halves each gather a FULL row per load
// (M=128: float4/lane, M=64: float2/lane). half0 = even edges, half1 = odd.
// Combine with shfl_xor(32); lanes<32 add self term, scale, store full row.
template <int M>
__global__ __launch_bounds__(256) void k_agg(const float* __restrict__ hp,
                                             const int* __restrict__ rowstart,
                                             const int* __restrict__ eidx,
                                             const float* __restrict__ dinv,
                                             const float* __restrict__ bias,
                                             float* __restrict__ out, int N) {
  int w = (blockIdx.x * 256 + threadIdx.x) >> 6;  // wave = node
  int lane = threadIdx.x & 63;
  int half = lane >> 5;
  int sub = lane & 31;
  if (w >= N) return;
  float di = dinv[w];
  int lo = rowstart[w], hi = rowstart[w + 1];
  if constexpr (M == 128) {
    float4 acc = make_float4(0.f, 0.f, 0.f, 0.f);
    int e = lo + half;
    for (; e + 6 < hi; e += 8) {  // 4 rows in flight per half-wave
      int s0 = eidx[e], s1 = eidx[e + 2], s2 = eidx[e + 4], s3 = eidx[e + 6];
      float4 v0 = *(const float4*)(hp + (size_t)s0 * 128 + sub * 4);
      float4 v1 = *(const float4*)(hp + (size_t)s1 * 128 + sub * 4);
      float4 v2 = *(const float4*)(hp + (size_t)s2 * 128 + sub * 4);
      float4 v3 = *(const float4*)(hp + (size_t)s3 * 128 + sub * 4);
      acc.x += (v0.x + v1.x) + (v2.x + v3.x);
      acc.y += (v0.y + v1.y) + (v2.y + v3.y);
      acc.z += (v0.z + v1.z) + (v2.z + v3.z);
      acc.w += (v0.w + v1.w) + (v2.w + v3.w);
    }
    for (; e < hi; e += 2) {
      int s = eidx[e];
      float4 v = *(const float4*)(hp + (size_t)s * 128 + sub * 4);
      acc.x += v.x;
      acc.y += v.y;
      acc.z += v.z;
      acc.w += v.w;
    }
    acc.x += __shfl_xor(acc.x, 32, 64);
    acc.y += __shfl_xor(acc.y, 32, 64);
    acc.z += __shfl_xor(acc.z, 32, 64);
    acc.w += __shfl_xor(acc.w, 32, 64);
    if (half == 0) {
      float4 self = *(const float4*)(hp + (size_t)w * 128 + sub * 4);
      float4 bb = *(const float4*)(bias + sub * 4);
      float4 r;
      r.x = (acc.x + self.x) * di + bb.x;
      r.y = (acc.y + self.y) * di + bb.y;
      r.z = (acc.z + self.z) * di + bb.z;
      r.w = (acc.w + self.w) * di + bb.w;
      *(float4*)(out + (size_t)w * 128 + sub * 4) = r;
    }
  } else {
    float2 acc = make_float2(0.f, 0.f);
    int e = lo + half;
    for (; e + 6 < hi; e += 8) {
      int s0 = eidx[e], s1 = eidx[e + 2], s2 = eidx[e + 4], s3 = eidx[e + 6];
      float2 v0 = *(const float2*)(hp + (size_t)s0 * 64 + sub * 2);
      float2 v1 = *(const float2*)(hp + (size_t)s1 * 64 + sub * 2);
      float2 v2 = *(const float2*)(hp + (size_t)s2 * 64 + sub * 2);
      float2 v3 = *(const float2*)(hp + (size_t)s3 * 64 + sub * 2);
      acc.x += (v0.x + v1.x) + (v2.x + v3.x);
      acc.y += (v0.y + v1.y) + (v2.y + v3.y);
    }
    for (; e < hi; e += 2) {
      int s = eidx[e];
      float2 v = *(const float2*)(hp + (size_t)s * 64 + sub * 2);
      acc.x += v.x;
      acc.y += v.y;
    }
    acc.x += __shfl_xor(acc.x, 32, 64);
    acc.y += __shfl_xor(acc.y, 32, 64);
    if (half == 0) {
      float2 self = *(const float2*)(hp + (size_t)w * 64 + sub * 2);
      float2 bb = *(const float2*)(bias + sub * 2);
      float2 r;
      r.x = (acc.x + self.x) * di + bb.x;
      r.y = (acc.y + self.y) * di + bb.y;
      *(float2*)(out + (size_t)w * 64 + sub * 2) = r;
    }
  }
}

// ---------------- pooling, parallel decomposition ----------------
__global__ __launch_bounds__(128) void k_gbounds(const int* __restrict__ batch,
                                                 int* __restrict__ gstart,
                                                 int N) {
  int g = threadIdx.x;
  if (g > GG) return;
  int lo = 0, hi = N;
  while (lo < hi) {
    int mid = (lo + hi) >> 1;
    if (batch[mid] < g) lo = mid + 1;
    else hi = mid;
  }
  gstart[g] = lo;
}

// chunked max over contiguous per-graph ranges: ONE atomicMax per block
__global__ __launch_bounds__(256) void k_pmax(const float* __restrict__ gate,
                                              const int* __restrict__ gstart,
                                              unsigned* __restrict__ gmaxu) {
  __shared__ unsigned red[256];
  const int g = blockIdx.x / CPB;
  const int c = blockIdx.x % CPB;
  const int lo = gstart[g], hi = gstart[g + 1];
  const int len = hi - lo;
  const int b0 = lo + (int)(((long long)len * c) / CPB);
  const int b1 = lo + (int)(((long long)len * (c + 1)) / CPB);
  unsigned mx = 0u;
  for (int i = b0 + threadIdx.x; i < b1; i += 256) mx = max(mx, fenc(gate[i]));
  red[threadIdx.x] = mx;
  __syncthreads();
  for (int o = 128; o; o >>= 1) {
    if (threadIdx.x < o)
      red[threadIdx.x] = max(red[threadIdx.x], red[threadIdx.x + o]);
    __syncthreads();
  }
  if (threadIdx.x == 0 && red[0] != 0u) atomicMax(&gmaxu[g], red[0]);
}

// grid = GG*CPB blocks, 256 thr (4 waves). lane=feature, wave strides nodes.
__global__ __launch_bounds__(256) void k_psum(const float* __restrict__ gate,
                                              const float* __restrict__ h3,
                                              const unsigned* __restrict__ gmaxu,
                                              const int* __restrict__ gstart,
                                              float* __restrict__ pooledw,
                                              float* __restrict__ ssum) {
  __shared__ float accs[4][64];
  __shared__ float ses[4];
  const int g = blockIdx.x / CPB;
  const int c = blockIdx.x % CPB;
  const int lo = gstart[g], hi = gstart[g + 1];
  const int len = hi - lo;
  const int b0 = lo + (int)(((long long)len * c) / CPB);
  const int b1 = lo + (int)(((long long)len * (c + 1)) / CPB);
  const int wave = threadIdx.x >> 6, lane = threadIdx.x & 63;
  const float m = fdec(gmaxu[g]);
  float acc = 0.f, se = 0.f;
  for (int i = b0 + wave; i < b1; i += 4) {
    float e = expf(gate[i] - m);
    acc += e * h3[(size_t)i * 64 + lane];
    se += e;
  }
  accs[wave][lane] = acc;
  if (lane == 0) ses[wave] = se;
  __syncthreads();
  if (threadIdx.x < 64) {
    float a = accs[0][threadIdx.x] + accs[1][threadIdx.x] +
              accs[2][threadIdx.x] + accs[3][threadIdx.x];
    if (a != 0.f) atomicAdd(&pooledw[g * 64 + threadIdx.x], a);
  }
  if (threadIdx.x == 64) {
    float s = ses[0] + ses[1] + ses[2] + ses[3];
    if (s != 0.f) atomicAdd(&ssum[g], s);
  }
}

// ---------------- head MLP (single block); normalization fused into P load --
__global__ __launch_bounds__(256) void k_head(const float* __restrict__ pooledw,
                                              const float* __restrict__ ssum,
                                              const float* __restrict__ Wm1,
                                              const float* __restrict__ bm1,
                                              const float* __restrict__ Wm2,
                                              const float* __restrict__ bm2,
                                              float* __restrict__ out) {
  __shared__ float P[64 * 64];
  __shared__ float T[64 * 128];
  int tid = threadIdx.x;
  for (int i = tid; i < 4096; i += 256) {
    float s = ssum[i >> 6];
    P[i] = pooledw[i] * ((s > 0.f) ? 1.0f / s : 0.f);
  }
  __syncthreads();
  for (int e = tid; e < 8192; e += 256) {
    int r = e >> 7, c = e & 127;
    float a = bm1[c];
    for (int k = 0; k < 64; ++k) a += P[r * 64 + k] * Wm1[k * 128 + c];
    T[e] = fmaxf(a, 0.f);
  }
  __syncthreads();
  for (int e = tid; e < 4096; e += 256) {
    int r = e >> 6, c = e & 63;
    float a = bm2[c];
    for (int k = 0; k < 128; ++k) a += T[r * 128 + k] * Wm2[k * 64 + c];
    out[e] = a;
  }
}

extern "C" void kernel_launch(void* const* d_in, const int* in_sizes, int n_in,
                              void* d_out, int out_size, void* d_ws,
                              size_t ws_size, hipStream_t stream) {
  const int N = NN, E = EE;
  const float* x = (const float*)d_in[0];
  const int* ei = (const int*)d_in[1];
  const int* batch = (const int*)d_in[2];
  const float* W1 = (const float*)d_in[3];
  const float* b1 = (const float*)d_in[4];
  const float* W2 = (const float*)d_in[5];
  const float* b2 = (const float*)d_in[6];
  const float* W3 = (const float*)d_in[7];
  const float* b3 = (const float*)d_in[8];
  const float* g1 = (const float*)d_in[9];
  const float* beta1 = (const float*)d_in[10];
  const float* g2 = (const float*)d_in[11];
  const float* beta2 = (const float*)d_in[12];
  const float* mean1 = (const float*)d_in[13];
  const float* var1 = (const float*)d_in[14];
  const float* mean2 = (const float*)d_in[15];
  const float* var2 = (const float*)d_in[16];
  const float* Wg1 = (const float*)d_in[17];
  const float* bg1 = (const float*)d_in[18];
  const float* Wg2 = (const float*)d_in[19];
  const float* bg2 = (const float*)d_in[20];
  const float* Wm1 = (const float*)d_in[21];
  const float* bm1 = (const float*)d_in[22];
  const float* Wm2 = (const float*)d_in[23];
  const float* bm2 = (const float*)d_in[24];
  float* out = (float*)d_out;

  const int* src = ei;
  const int* dst = ei + E;

  char* wsb = (char*)d_ws;
  size_t off = 0;
  auto alloc = [&](size_t elems) -> void* {
    void* p = wsb + off;
    off += elems * 4;
    return p;
  };
  int* cnt = (int*)alloc(N);
  int* rowstart = (int*)alloc(N + 4);
  int* cursor = (int*)alloc(N);
  int* eidx = (int*)alloc(E);
  float* dinv = (float*)alloc(N);
  float* gate = (float*)alloc(N);
  float* bufA = (float*)alloc((size_t)N * 128);
  float* bufB = (float*)alloc((size_t)N * 128);
  int* bsum = (int*)alloc(256);
  int* boff = (int*)alloc(256);
  short* wt = (short*)alloc(49152);  // 98304 shorts
  float* bn1s = (float*)alloc(128);
  float* bn1h = (float*)alloc(128);
  float* bn2s = (float*)alloc(128);
  float* bn2h = (float*)alloc(128);
  // pooling buffers (contiguous for one memset): pooledw + ssum + gmaxu
  float* pooledw = (float*)alloc(GG * 64);
  float* ssum = (float*)alloc(GG);
  unsigned* gmaxu = (unsigned*)alloc(GG);
  int* gstart = (int*)alloc(GG + 4);
  (void)ws_size;
  (void)n_in;
  (void)in_sizes;
  (void)out_size;

  const int nscan = (N + SB - 1) / SB;

  // CSR build (once, reused for all 3 conv layers)
  hipMemsetAsync(cnt, 0, N * sizeof(int), stream);
  hipMemsetAsync(pooledw, 0, (GG * 64 + GG + GG) * sizeof(float), stream);
  k_count<<<(E + 255) / 256, 256, 0, stream>>>(dst, cnt, E);
  k_scan1<<<nscan, SB, 0, stream>>>(cnt, dinv, bsum, N);
  k_scan2<<<1, 256, 0, stream>>>(bsum, boff, nscan, rowstart + N);
  k_scan3<<<nscan, SB, 0, stream>>>(cnt, boff, rowstart, cursor, N);
  k_fill<<<(E + 255) / 256, 256, 0, stream>>>(src, dst, cursor, eidx, E);

  // weight/bn prep + graph bounds
  k_wsplit<<<192, 256, 0, stream>>>(W1, W2, W3, Wg1, wt);
  k_bnprep<<<1, 256, 0, stream>>>(g1, beta1, mean1, var1, g2, beta2, mean2,
                                  var2, bn1s, bn1h, bn2s, bn2h);
  k_gbounds<<<1, 128, 0, stream>>>(batch, gstart, N);

  const int gb = (N + 63) / 64;         // GEMM blocks (64 rows each)
  const int ab = (N * 64 + 255) / 256;  // agg blocks (wave per node)

  // Layer 1: h1' = (x@W1)*dinv ; agg
  k_mgemm<128, 128, 0, 1, 0><<<gb, 256, 0, stream>>>(
      x, wt, wt + 16384, nullptr, nullptr, dinv, nullptr, nullptr, nullptr,
      bufA, nullptr, N);
  k_agg<128><<<ab, 256, 0, stream>>>(bufA, rowstart, eidx, dinv, b1, bufB, N);

  // Layer 2 (BN1+relu fused into A load)
  k_mgemm<128, 128, 1, 1, 0><<<gb, 256, 0, stream>>>(
      bufB, wt + 32768, wt + 49152, bn1s, bn1h, dinv, nullptr, nullptr,
      nullptr, bufA, nullptr, N);
  k_agg<128><<<ab, 256, 0, stream>>>(bufA, rowstart, eidx, dinv, b2, bufB, N);

  // Layer 3 (M=64, BN2 fused)
  k_mgemm<128, 64, 1, 1, 0><<<gb, 256, 0, stream>>>(
      bufB, wt + 65536, wt + 73728, bn2s, bn2h, dinv, nullptr, nullptr,
      nullptr, bufA, nullptr, N);
  k_agg<64><<<ab, 256, 0, stream>>>(bufA, rowstart, eidx, dinv, b3, bufB, N);
  // h3 = bufB (N x 64)

  // gate = relu(h3@Wg1+bg1)@Wg2+bg2 (fused epilogue)
  k_mgemm<64, 128, 0, 0, 1><<<gb, 256, 0, stream>>>(
      bufB, wt + 81920, wt + 90112, nullptr, nullptr, nullptr, bg1, Wg2, bg2,
      nullptr, gate, N);

  // softmax pooling (parallel): chunked max -> exp-sums -> (normalize in head)
  k_pmax<<<GG * CPB, 256, 0, stream>>>(gate, gstart, gmaxu);
  k_psum<<<GG * CPB, 256, 0, stream>>>(gate, bufB, gmaxu, gstart, pooledw,
                                       ssum);

  // head MLP
  k_head<<<1, 256, 0, stream>>>(pooledw, ssum, Wm1, bm1, Wm2, bm2, out);
}

// Round 8
// 669.414 us; speedup vs baseline: 1.7616x; 1.1311x over previous
//
#include <hip/hip_runtime.h>
#include <hip/hip_bf16.h>
#include <hip/hip_fp16.h>
#include <math.h>

#define NN 100000
#define EE 1000000
#define GG 64
#define BN_EPS 1e-5f
#define SB 512  // scan block size
#define CPB 16  // pooling chunks per graph

typedef __attribute__((ext_vector_type(8))) short bf16x8;
typedef __attribute__((ext_vector_type(4))) float f32x4;

// float -> bf16 (RNE) and back, as raw shorts
__device__ inline short f2bf(float f) {
  unsigned u = __float_as_uint(f);
  u = u + 0x7fff + ((u >> 16) & 1);
  return (short)(u >> 16);
}
__device__ inline float bf2f(short h) {
  return __uint_as_float(((unsigned)(unsigned short)h) << 16);
}

// order-preserving float<->uint transform (for atomicMax on floats)
__device__ inline unsigned fenc(float f) {
  int b = __float_as_int(f);
  return (b < 0) ? ~(unsigned)b : ((unsigned)b | 0x80000000u);
}
__device__ inline float fdec(unsigned u) {
  int b = (u & 0x80000000u) ? (int)(u & 0x7fffffffu) : (int)~u;
  return __int_as_float(b);
}

// ---------------- degree count ----------------
__global__ __launch_bounds__(256) void k_count(const int* __restrict__ dst,
                                               int* __restrict__ cnt, int E) {
  int i = blockIdx.x * 256 + threadIdx.x;
  if (i < E) atomicAdd(&cnt[dst[i]], 1);
}

// ---------------- hierarchical scan ----------------
__global__ __launch_bounds__(SB) void k_scan1(const int* __restrict__ cnt,
                                              float* __restrict__ dinv,
                                              int* __restrict__ bsum, int N) {
  __shared__ int red[SB];
  int t = threadIdx.x;
  int i = blockIdx.x * SB + t;
  int v = (i < N) ? cnt[i] : 0;
  if (i < N) dinv[i] = rsqrtf(1.0f + (float)v);
  red[t] = v;
  __syncthreads();
  for (int o = SB / 2; o; o >>= 1) {
    if (t < o) red[t] += red[t + o];
    __syncthreads();
  }
  if (t == 0) bsum[blockIdx.x] = red[0];
}

__global__ __launch_bounds__(256) void k_scan2(const int* __restrict__ bsum,
                                               int* __restrict__ boff, int nb,
                                               int* __restrict__ total_out) {
  __shared__ int s[256];
  int t = threadIdx.x;
  int v = (t < nb) ? bsum[t] : 0;
  s[t] = v;
  __syncthreads();
  for (int o = 1; o < 256; o <<= 1) {
    int u = (t >= o) ? s[t - o] : 0;
    __syncthreads();
    s[t] += u;
    __syncthreads();
  }
  boff[t] = s[t] - v;  // exclusive
  if (t == 255) *total_out = s[255];
}

__global__ __launch_bounds__(SB) void k_scan3(const int* __restrict__ cnt,
                                              const int* __restrict__ boff,
                                              int* __restrict__ rowstart,
                                              int* __restrict__ cursor, int N) {
  __shared__ int s[SB];
  int t = threadIdx.x;
  int i = blockIdx.x * SB + t;
  int v = (i < N) ? cnt[i] : 0;
  s[t] = v;
  __syncthreads();
  for (int o = 1; o < SB; o <<= 1) {
    int u = (t >= o) ? s[t - o] : 0;
    __syncthreads();
    s[t] += u;
    __syncthreads();
  }
  int excl = s[t] - v + boff[blockIdx.x];
  if (i < N) {
    rowstart[i] = excl;
    cursor[i] = excl;
  }
}

__global__ __launch_bounds__(256) void k_fill(const int* __restrict__ src,
                                              const int* __restrict__ dst,
                                              int* __restrict__ cursor,
                                              int* __restrict__ eidx, int E) {
  int i = blockIdx.x * 256 + threadIdx.x;
  if (i < E) {
    int pos = atomicAdd(&cursor[dst[i]], 1);
    eidx[pos] = src[i];
  }
}

// ---------------- weight prep: transpose + split into bf16 hi/lo ----------------
__global__ __launch_bounds__(256) void k_wsplit(const float* __restrict__ W1,
                                                const float* __restrict__ W2,
                                                const float* __restrict__ W3,
                                                const float* __restrict__ Wg1,
                                                short* __restrict__ wt) {
  int i = blockIdx.x * 256 + threadIdx.x;
  const float* W;
  short *hi, *lo;
  int K, M, idx;
  if (i < 16384) {
    W = W1; hi = wt; lo = wt + 16384; K = 128; M = 128; idx = i;
  } else if (i < 32768) {
    W = W2; hi = wt + 32768; lo = wt + 49152; K = 128; M = 128; idx = i - 16384;
  } else if (i < 40960) {
    W = W3; hi = wt + 65536; lo = wt + 73728; K = 128; M = 64; idx = i - 32768;
  } else {
    W = Wg1; hi = wt + 81920; lo = wt + 90112; K = 64; M = 128; idx = i - 40960;
  }
  int k = idx / M, n = idx % M;
  float w = W[idx];
  short h = f2bf(w);
  hi[n * K + k] = h;
  lo[n * K + k] = f2bf(w - bf2f(h));
}

// ---------------- BN prep ----------------
__global__ __launch_bounds__(256) void k_bnprep(
    const float* __restrict__ g1, const float* __restrict__ b1,
    const float* __restrict__ m1, const float* __restrict__ v1,
    const float* __restrict__ g2, const float* __restrict__ b2,
    const float* __restrict__ m2, const float* __restrict__ v2,
    float* __restrict__ s1, float* __restrict__ h1, float* __restrict__ s2,
    float* __restrict__ h2) {
  int i = threadIdx.x;
  if (i < 128) {
    float s = g1[i] * rsqrtf(v1[i] + BN_EPS);
    s1[i] = s;
    h1[i] = b1[i] - m1[i] * s;
  } else {
    int j = i - 128;
    float s = g2[j] * rsqrtf(v2[j] + BN_EPS);
    s2[j] = s;
    h2[j] = b2[j] - m2[j] * s;
  }
}

// ---------------- MFMA split-bf16 GEMM ----------------
// OUTH: write output as fp16 (halves gather bytes for the following k_agg)
template <int K, int M, int BN, int DINV, int GATE, int OUTH>
__global__ __launch_bounds__(256, 4) void k_mgemm(
    const float* __restrict__ X, const short* __restrict__ Wthi,
    const short* __restrict__ Wtlo, const float* __restrict__ bns,
    const float* __restrict__ bnh, const float* __restrict__ dinv,
    const float* __restrict__ gbias, const float* __restrict__ Wg2v,
    const float* __restrict__ bg2v, void* __restrict__ Y,
    float* __restrict__ gate, int nrows) {
  constexpr int NC = K / 32;  // k chunks of 32
  constexpr int CT = M / 16;  // 16-col tiles
  const int lane = threadIdx.x & 63;
  const int wave = threadIdx.x >> 6;
  const int m16 = lane & 15;
  const int quad = lane >> 4;
  const int rowbase = blockIdx.x * 64 + wave * 16;
  const int arow = rowbase + m16;
  const bool rok = arow < nrows;

  bf16x8 ahi[NC], alo[NC];
#pragma unroll
  for (int c = 0; c < NC; ++c) {
    const int k0 = c * 32 + quad * 8;
    float4 v0 = make_float4(0.f, 0.f, 0.f, 0.f), v1 = v0;
    if (rok) {
      v0 = *(const float4*)(X + (size_t)arow * K + k0);
      v1 = *(const float4*)(X + (size_t)arow * K + k0 + 4);
    }
    float vv[8] = {v0.x, v0.y, v0.z, v0.w, v1.x, v1.y, v1.z, v1.w};
    if constexpr (BN) {
#pragma unroll
      for (int j = 0; j < 8; ++j)
        vv[j] = fmaxf(vv[j] * bns[k0 + j] + bnh[k0 + j], 0.f);
    }
#pragma unroll
    for (int j = 0; j < 8; ++j) {
      short h = f2bf(vv[j]);
      ahi[c][j] = h;
      alo[c][j] = f2bf(vv[j] - bf2f(h));
    }
  }

  float gp[4] = {0.f, 0.f, 0.f, 0.f};
#pragma unroll
  for (int ct = 0; ct < CT; ++ct) {
    f32x4 acc = {0.f, 0.f, 0.f, 0.f};
    const size_t wrow = (size_t)(ct * 16 + m16) * K + quad * 8;
#pragma unroll
    for (int c = 0; c < NC; ++c) {
      bf16x8 bhi = *(const bf16x8*)(Wthi + wrow + c * 32);
      bf16x8 blo = *(const bf16x8*)(Wtlo + wrow + c * 32);
      acc = __builtin_amdgcn_mfma_f32_16x16x32_bf16(ahi[c], bhi, acc, 0, 0, 0);
      acc = __builtin_amdgcn_mfma_f32_16x16x32_bf16(ahi[c], blo, acc, 0, 0, 0);
      acc = __builtin_amdgcn_mfma_f32_16x16x32_bf16(alo[c], bhi, acc, 0, 0, 0);
    }
    if constexpr (GATE) {
      const int col = ct * 16 + m16;
      const float gb = gbias[col], wg = Wg2v[col];
#pragma unroll
      for (int r = 0; r < 4; ++r) gp[r] += fmaxf(acc[r] + gb, 0.f) * wg;
    } else {
#pragma unroll
      for (int r = 0; r < 4; ++r) {
        const int row = rowbase + quad * 4 + r;
        if (row < nrows) {
          float v = acc[r];
          if constexpr (DINV) v *= dinv[row];
          if constexpr (OUTH)
            ((__half*)Y)[(size_t)row * M + ct * 16 + m16] = __float2half(v);
          else
            ((float*)Y)[(size_t)row * M + ct * 16 + m16] = v;
        }
      }
    }
  }
  if constexpr (GATE) {
#pragma unroll
    for (int o = 1; o < 16; o <<= 1) {
#pragma unroll
      for (int r = 0; r < 4; ++r) gp[r] += __shfl_xor(gp[r], o, 64);
    }
    if (m16 == 0) {
      const float b2 = bg2v[0];
#pragma unroll
      for (int r = 0; r < 4; ++r) {
        const int row = rowbase + quad * 4 + r;
        if (row < nrows) gate[row] = gp[r] + b2;
      }
    }
  }
}

// ---------------- GCN aggregation (gather over CSR by dst, fp16 rows) -------
// hp is fp16 (pre-scaled by dinv in GEMM). out[n] (fp32) =
//   dinv[n]*(sum hp[src] + hp[n]) + bias.
// wave = node; two 32-lane halves each gather a FULL row per load
// (M=128: 4 halves/lane = 8B, M=64: 2 halves/lane = 4B); halves take
// even/odd edges, combined via shfl_xor(32); lanes<32 store fp32 row.
__device__ inline void acc_h4(float4& a, uint2 u) {
  __half2 h0 = *(__half2*)&u.x;
  __half2 h1 = *(__half2*)&u.y;
  float2 f0 = __half22float2(h0), f1 = __half22float2(h1);
  a.x += f0.x;
  a.y += f0.y;
  a.z += f1.x;
  a.w += f1.y;
}
__device__ inline void acc_h2(float2& a, unsigned u) {
  float2 f = __half22float2(*(__half2*)&u);
  a.x += f.x;
  a.y += f.y;
}

template <int M>
__global__ __launch_bounds__(256) void k_agg(const __half* __restrict__ hp,
                                             const int* __restrict__ rowstart,
                                             const int* __restrict__ eidx,
                                             const float* __restrict__ dinv,
                                             const float* __restrict__ bias,
                                             float* __restrict__ out, int N) {
  int w = (blockIdx.x * 256 + threadIdx.x) >> 6;  // wave = node
  int lane = threadIdx.x & 63;
  int half_ = lane >> 5;
  int sub = lane & 31;
  if (w >= N) return;
  float di = dinv[w];
  int lo = rowstart[w], hi = rowstart[w + 1];
  if constexpr (M == 128) {
    float4 acc = make_float4(0.f, 0.f, 0.f, 0.f);
    int e = lo + half_;
    for (; e + 6 < hi; e += 8) {  // 4 rows in flight per half-wave
      int s0 = eidx[e], s1 = eidx[e + 2], s2 = eidx[e + 4], s3 = eidx[e + 6];
      uint2 u0 = *(const uint2*)(hp + (size_t)s0 * 128 + sub * 4);
      uint2 u1 = *(const uint2*)(hp + (size_t)s1 * 128 + sub * 4);
      uint2 u2 = *(const uint2*)(hp + (size_t)s2 * 128 + sub * 4);
      uint2 u3 = *(const uint2*)(hp + (size_t)s3 * 128 + sub * 4);
      acc_h4(acc, u0);
      acc_h4(acc, u1);
      acc_h4(acc, u2);
      acc_h4(acc, u3);
    }
    for (; e < hi; e += 2) {
      uint2 u = *(const uint2*)(hp + (size_t)eidx[e] * 128 + sub * 4);
      acc_h4(acc, u);
    }
    acc.x += __shfl_xor(acc.x, 32, 64);
    acc.y += __shfl_xor(acc.y, 32, 64);
    acc.z += __shfl_xor(acc.z, 32, 64);
    acc.w += __shfl_xor(acc.w, 32, 64);
    if (half_ == 0) {
      float4 self = make_float4(0.f, 0.f, 0.f, 0.f);
      acc_h4(self, *(const uint2*)(hp + (size_t)w * 128 + sub * 4));
      float4 bb = *(const float4*)(bias + sub * 4);
      float4 r;
      r.x = (acc.x + self.x) * di + bb.x;
      r.y = (acc.y + self.y) * di + bb.y;
      r.z = (acc.z + self.z) * di + bb.z;
      r.w = (acc.w + self.w) * di + bb.w;
      *(float4*)(out + (size_t)w * 128 + sub * 4) = r;
    }
  } else {
    float2 acc = make_float2(0.f, 0.f);
    int e = lo + half_;
    for (; e + 6 < hi; e += 8) {
      int s0 = eidx[e], s1 = eidx[e + 2], s2 = eidx[e + 4], s3 = eidx[e + 6];
      unsigned u0 = *(const unsigned*)(hp + (size_t)s0 * 64 + sub * 2);
      unsigned u1 = *(const unsigned*)(hp + (size_t)s1 * 64 + sub * 2);
      unsigned u2 = *(const unsigned*)(hp + (size_t)s2 * 64 + sub * 2);
      unsigned u3 = *(const unsigned*)(hp + (size_t)s3 * 64 + sub * 2);
      acc_h2(acc, u0);
      acc_h2(acc, u1);
      acc_h2(acc, u2);
      acc_h2(acc, u3);
    }
    for (; e < hi; e += 2) {
      unsigned u = *(const unsigned*)(hp + (size_t)eidx[e] * 64 + sub * 2);
      acc_h2(acc, u);
    }
    acc.x += __shfl_xor(acc.x, 32, 64);
    acc.y += __shfl_xor(acc.y, 32, 64);
    if (half_ == 0) {
      float2 self = make_float2(0.f, 0.f);
      acc_h2(self, *(const unsigned*)(hp + (size_t)w * 64 + sub * 2));
      float2 bb = *(const float2*)(bias + sub * 2);
      float2 r;
      r.x = (acc.x + self.x) * di + bb.x;
      r.y = (acc.y + self.y) * di + bb.y;
      *(float2*)(out + (size_t)w * 64 + sub * 2) = r;
    }
  }
}

// ---------------- pooling, parallel decomposition ----------------
__global__ __launch_bounds__(128) void k_gbounds(const int* __restrict__ batch,
                                                 int* __restrict__ gstart,
                                                 int N) {
  int g = threadIdx.x;
  if (g > GG) return;
  int lo = 0, hi = N;
  while (lo < hi) {
    int mid = (lo + hi) >> 1;
    if (batch[mid] < g) lo = mid + 1;
    else hi = mid;
  }
  gstart[g] = lo;
}

// chunked max over contiguous per-graph ranges: ONE atomicMax per block
__global__ __launch_bounds__(256) void k_pmax(const float* __restrict__ gate,
                                              const int* __restrict__ gstart,
                                              unsigned* __restrict__ gmaxu) {
  __shared__ unsigned red[256];
  const int g = blockIdx.x / CPB;
  const int c = blockIdx.x % CPB;
  const int lo = gstart[g], hi = gstart[g + 1];
  const int len = hi - lo;
  const int b0 = lo + (int)(((long long)len * c) / CPB);
  const int b1 = lo + (int)(((long long)len * (c + 1)) / CPB);
  unsigned mx = 0u;
  for (int i = b0 + threadIdx.x; i < b1; i += 256) mx = max(mx, fenc(gate[i]));
  red[threadIdx.x] = mx;
  __syncthreads();
  for (int o = 128; o; o >>= 1) {
    if (threadIdx.x < o)
      red[threadIdx.x] = max(red[threadIdx.x], red[threadIdx.x + o]);
    __syncthreads();
  }
  if (threadIdx.x == 0 && red[0] != 0u) atomicMax(&gmaxu[g], red[0]);
}

// grid = GG*CPB blocks, 256 thr (4 waves). lane=feature, wave strides nodes.
__global__ __launch_bounds__(256) void k_psum(const float* __restrict__ gate,
                                              const float* __restrict__ h3,
                                              const unsigned* __restrict__ gmaxu,
                                              const int* __restrict__ gstart,
                                              float* __restrict__ pooledw,
                                              float* __restrict__ ssum) {
  __shared__ float accs[4][64];
  __shared__ float ses[4];
  const int g = blockIdx.x / CPB;
  const int c = blockIdx.x % CPB;
  const int lo = gstart[g], hi = gstart[g + 1];
  const int len = hi - lo;
  const int b0 = lo + (int)(((long long)len * c) / CPB);
  const int b1 = lo + (int)(((long long)len * (c + 1)) / CPB);
  const int wave = threadIdx.x >> 6, lane = threadIdx.x & 63;
  const float m = fdec(gmaxu[g]);
  float acc = 0.f, se = 0.f;
  for (int i = b0 + wave; i < b1; i += 4) {
    float e = expf(gate[i] - m);
    acc += e * h3[(size_t)i * 64 + lane];
    se += e;
  }
  accs[wave][lane] = acc;
  if (lane == 0) ses[wave] = se;
  __syncthreads();
  if (threadIdx.x < 64) {
    float a = accs[0][threadIdx.x] + accs[1][threadIdx.x] +
              accs[2][threadIdx.x] + accs[3][threadIdx.x];
    if (a != 0.f) atomicAdd(&pooledw[g * 64 + threadIdx.x], a);
  }
  if (threadIdx.x == 64) {
    float s = ses[0] + ses[1] + ses[2] + ses[3];
    if (s != 0.f) atomicAdd(&ssum[g], s);
  }
}

// ---------------- head MLP (single block); normalization fused into P load --
__global__ __launch_bounds__(256) void k_head(const float* __restrict__ pooledw,
                                              const float* __restrict__ ssum,
                                              const float* __restrict__ Wm1,
                                              const float* __restrict__ bm1,
                                              const float* __restrict__ Wm2,
                                              const float* __restrict__ bm2,
                                              float* __restrict__ out) {
  __shared__ float P[64 * 64];
  __shared__ float T[64 * 128];
  int tid = threadIdx.x;
  for (int i = tid; i < 4096; i += 256) {
    float s = ssum[i >> 6];
    P[i] = pooledw[i] * ((s > 0.f) ? 1.0f / s : 0.f);
  }
  __syncthreads();
  for (int e = tid; e < 8192; e += 256) {
    int r = e >> 7, c = e & 127;
    float a = bm1[c];
    for (int k = 0; k < 64; ++k) a += P[r * 64 + k] * Wm1[k * 128 + c];
    T[e] = fmaxf(a, 0.f);
  }
  __syncthreads();
  for (int e = tid; e < 4096; e += 256) {
    int r = e >> 6, c = e & 63;
    float a = bm2[c];
    for (int k = 0; k < 128; ++k) a += T[r * 128 + k] * Wm2[k * 64 + c];
    out[e] = a;
  }
}

extern "C" void kernel_launch(void* const* d_in, const int* in_sizes, int n_in,
                              void* d_out, int out_size, void* d_ws,
                              size_t ws_size, hipStream_t stream) {
  const int N = NN, E = EE;
  const float* x = (const float*)d_in[0];
  const int* ei = (const int*)d_in[1];
  const int* batch = (const int*)d_in[2];
  const float* W1 = (const float*)d_in[3];
  const float* b1 = (const float*)d_in[4];
  const float* W2 = (const float*)d_in[5];
  const float* b2 = (const float*)d_in[6];
  const float* W3 = (const float*)d_in[7];
  const float* b3 = (const float*)d_in[8];
  const float* g1 = (const float*)d_in[9];
  const float* beta1 = (const float*)d_in[10];
  const float* g2 = (const float*)d_in[11];
  const float* beta2 = (const float*)d_in[12];
  const float* mean1 = (const float*)d_in[13];
  const float* var1 = (const float*)d_in[14];
  const float* mean2 = (const float*)d_in[15];
  const float* var2 = (const float*)d_in[16];
  const float* Wg1 = (const float*)d_in[17];
  const float* bg1 = (const float*)d_in[18];
  const float* Wg2 = (const float*)d_in[19];
  const float* bg2 = (const float*)d_in[20];
  const float* Wm1 = (const float*)d_in[21];
  const float* bm1 = (const float*)d_in[22];
  const float* Wm2 = (const float*)d_in[23];
  const float* bm2 = (const float*)d_in[24];
  float* out = (float*)d_out;

  const int* src = ei;
  const int* dst = ei + E;

  char* wsb = (char*)d_ws;
  size_t off = 0;
  auto alloc = [&](size_t elems) -> void* {
    void* p = wsb + off;
    off += elems * 4;
    return p;
  };
  int* cnt = (int*)alloc(N);
  int* rowstart = (int*)alloc(N + 4);
  int* cursor = (int*)alloc(N);
  int* eidx = (int*)alloc(E);
  float* dinv = (float*)alloc(N);
  float* gate = (float*)alloc(N);
  __half* hbuf = (__half*)alloc((size_t)N * 64);   // fp16 N x 128 plane
  float* fbuf = (float*)alloc((size_t)N * 128);    // fp32 N x 128 plane
  int* bsum = (int*)alloc(256);
  int* boff = (int*)alloc(256);
  short* wt = (short*)alloc(49152);  // 98304 shorts
  float* bn1s = (float*)alloc(128);
  float* bn1h = (float*)alloc(128);
  float* bn2s = (float*)alloc(128);
  float* bn2h = (float*)alloc(128);
  // pooling buffers (contiguous for one memset): pooledw + ssum + gmaxu
  float* pooledw = (float*)alloc(GG * 64);
  float* ssum = (float*)alloc(GG);
  unsigned* gmaxu = (unsigned*)alloc(GG);
  int* gstart = (int*)alloc(GG + 4);
  (void)ws_size;
  (void)n_in;
  (void)in_sizes;
  (void)out_size;

  const int nscan = (N + SB - 1) / SB;

  // CSR build (once, reused for all 3 conv layers)
  hipMemsetAsync(cnt, 0, N * sizeof(int), stream);
  hipMemsetAsync(pooledw, 0, (GG * 64 + GG + GG) * sizeof(float), stream);
  k_count<<<(E + 255) / 256, 256, 0, stream>>>(dst, cnt, E);
  k_scan1<<<nscan, SB, 0, stream>>>(cnt, dinv, bsum, N);
  k_scan2<<<1, 256, 0, stream>>>(bsum, boff, nscan, rowstart + N);
  k_scan3<<<nscan, SB, 0, stream>>>(cnt, boff, rowstart, cursor, N);
  k_fill<<<(E + 255) / 256, 256, 0, stream>>>(src, dst, cursor, eidx, E);

  // weight/bn prep + graph bounds
  k_wsplit<<<192, 256, 0, stream>>>(W1, W2, W3, Wg1, wt);
  k_bnprep<<<1, 256, 0, stream>>>(g1, beta1, mean1, var1, g2, beta2, mean2,
                                  var2, bn1s, bn1h, bn2s, bn2h);
  k_gbounds<<<1, 128, 0, stream>>>(batch, gstart, N);

  const int gb = (N + 63) / 64;         // GEMM blocks (64 rows each)
  const int ab = (N * 64 + 255) / 256;  // agg blocks (wave per node)

  // Layer 1: hp1 = fp16((x@W1)*dinv) ; agg -> fbuf (fp32)
  k_mgemm<128, 128, 0, 1, 0, 1><<<gb, 256, 0, stream>>>(
      x, wt, wt + 16384, nullptr, nullptr, dinv, nullptr, nullptr, nullptr,
      hbuf, nullptr, N);
  k_agg<128><<<ab, 256, 0, stream>>>(hbuf, rowstart, eidx, dinv, b1, fbuf, N);

  // Layer 2 (BN1+relu fused into A load)
  k_mgemm<128, 128, 1, 1, 0, 1><<<gb, 256, 0, stream>>>(
      fbuf, wt + 32768, wt + 49152, bn1s, bn1h, dinv, nullptr, nullptr,
      nullptr, hbuf, nullptr, N);
  k_agg<128><<<ab, 256, 0, stream>>>(hbuf, rowstart, eidx, dinv, b2, fbuf, N);

  // Layer 3 (M=64, BN2 fused)
  k_mgemm<128, 64, 1, 1, 0, 1><<<gb, 256, 0, stream>>>(
      fbuf, wt + 65536, wt + 73728, bn2s, bn2h, dinv, nullptr, nullptr,
      nullptr, hbuf, nullptr, N);
  k_agg<64><<<ab, 256, 0, stream>>>(hbuf, rowstart, eidx, dinv, b3, fbuf, N);
  // h3 = fbuf (N x 64, fp32)

  // gate = relu(h3@Wg1+bg1)@Wg2+bg2 (fused epilogue)
  k_mgemm<64, 128, 0, 0, 1, 0><<<gb, 256, 0, stream>>>(
      fbuf, wt + 81920, wt + 90112, nullptr, nullptr, nullptr, bg1, Wg2, bg2,
      nullptr, gate, N);

  // softmax pooling (parallel): chunked max -> exp-sums -> (normalize in head)
  k_pmax<<<GG * CPB, 256, 0, stream>>>(gate, gstart, gmaxu);
  k_psum<<<GG * CPB, 256, 0, stream>>>(gate, fbuf, gmaxu, gstart, pooledw,
                                       ssum);

  // head MLP
  k_head<<<1, 256, 0, stream>>>(pooledw, ssum, Wm1, bm1, Wm2, bm2, out);
}

// Round 9
// 573.348 us; speedup vs baseline: 2.0568x; 1.1676x over previous
//
#include <hip/hip_runtime.h>
#include <hip/hip_bf16.h>
#include <hip/hip_fp16.h>
#include <math.h>

#define NN 100000
#define EE 1000000
#define GG 64
#define BN_EPS 1e-5f
#define SB 512  // scan block size
#define CPB 16  // pooling chunks per graph

typedef __attribute__((ext_vector_type(8))) short bf16x8;
typedef __attribute__((ext_vector_type(4))) float f32x4;

// float -> bf16 (RNE) and back, as raw shorts
__device__ inline short f2bf(float f) {
  unsigned u = __float_as_uint(f);
  u = u + 0x7fff + ((u >> 16) & 1);
  return (short)(u >> 16);
}
__device__ inline float bf2f(short h) {
  return __uint_as_float(((unsigned)(unsigned short)h) << 16);
}

// order-preserving float<->uint transform (for atomicMax on floats)
__device__ inline unsigned fenc(float f) {
  int b = __float_as_int(f);
  return (b < 0) ? ~(unsigned)b : ((unsigned)b | 0x80000000u);
}
__device__ inline float fdec(unsigned u) {
  int b = (u & 0x80000000u) ? (int)(u & 0x7fffffffu) : (int)~u;
  return __int_as_float(b);
}

// ---------------- degree count ----------------
__global__ __launch_bounds__(256) void k_count(const int* __restrict__ dst,
                                               int* __restrict__ cnt, int E) {
  int i = blockIdx.x * 256 + threadIdx.x;
  if (i < E) atomicAdd(&cnt[dst[i]], 1);
}

// ---------------- hierarchical scan ----------------
__global__ __launch_bounds__(SB) void k_scan1(const int* __restrict__ cnt,
                                              float* __restrict__ dinv,
                                              int* __restrict__ bsum, int N) {
  __shared__ int red[SB];
  int t = threadIdx.x;
  int i = blockIdx.x * SB + t;
  int v = (i < N) ? cnt[i] : 0;
  if (i < N) dinv[i] = rsqrtf(1.0f + (float)v);
  red[t] = v;
  __syncthreads();
  for (int o = SB / 2; o; o >>= 1) {
    if (t < o) red[t] += red[t + o];
    __syncthreads();
  }
  if (t == 0) bsum[blockIdx.x] = red[0];
}

__global__ __launch_bounds__(256) void k_scan2(const int* __restrict__ bsum,
                                               int* __restrict__ boff, int nb,
                                               int* __restrict__ total_out) {
  __shared__ int s[256];
  int t = threadIdx.x;
  int v = (t < nb) ? bsum[t] : 0;
  s[t] = v;
  __syncthreads();
  for (int o = 1; o < 256; o <<= 1) {
    int u = (t >= o) ? s[t - o] : 0;
    __syncthreads();
    s[t] += u;
    __syncthreads();
  }
  boff[t] = s[t] - v;  // exclusive
  if (t == 255) *total_out = s[255];
}

__global__ __launch_bounds__(SB) void k_scan3(const int* __restrict__ cnt,
                                              const int* __restrict__ boff,
                                              int* __restrict__ rowstart,
                                              int* __restrict__ cursor, int N) {
  __shared__ int s[SB];
  int t = threadIdx.x;
  int i = blockIdx.x * SB + t;
  int v = (i < N) ? cnt[i] : 0;
  s[t] = v;
  __syncthreads();
  for (int o = 1; o < SB; o <<= 1) {
    int u = (t >= o) ? s[t - o] : 0;
    __syncthreads();
    s[t] += u;
    __syncthreads();
  }
  int excl = s[t] - v + boff[blockIdx.x];
  if (i < N) {
    rowstart[i] = excl;
    cursor[i] = excl;
  }
}

__global__ __launch_bounds__(256) void k_fill(const int* __restrict__ src,
                                              const int* __restrict__ dst,
                                              int* __restrict__ cursor,
                                              int* __restrict__ eidx, int E) {
  int i = blockIdx.x * 256 + threadIdx.x;
  if (i < E) {
    int pos = atomicAdd(&cursor[dst[i]], 1);
    eidx[pos] = src[i];
  }
}

// ---------------- weight prep: transpose + split into bf16 hi/lo ----------------
__global__ __launch_bounds__(256) void k_wsplit(const float* __restrict__ W1,
                                                const float* __restrict__ W2,
                                                const float* __restrict__ W3,
                                                const float* __restrict__ Wg1,
                                                short* __restrict__ wt) {
  int i = blockIdx.x * 256 + threadIdx.x;
  const float* W;
  short *hi, *lo;
  int K, M, idx;
  if (i < 16384) {
    W = W1; hi = wt; lo = wt + 16384; K = 128; M = 128; idx = i;
  } else if (i < 32768) {
    W = W2; hi = wt + 32768; lo = wt + 49152; K = 128; M = 128; idx = i - 16384;
  } else if (i < 40960) {
    W = W3; hi = wt + 65536; lo = wt + 73728; K = 128; M = 64; idx = i - 32768;
  } else {
    W = Wg1; hi = wt + 81920; lo = wt + 90112; K = 64; M = 128; idx = i - 40960;
  }
  int k = idx / M, n = idx % M;
  float w = W[idx];
  short h = f2bf(w);
  hi[n * K + k] = h;
  lo[n * K + k] = f2bf(w - bf2f(h));
}

// ---------------- BN prep ----------------
__global__ __launch_bounds__(256) void k_bnprep(
    const float* __restrict__ g1, const float* __restrict__ b1,
    const float* __restrict__ m1, const float* __restrict__ v1,
    const float* __restrict__ g2, const float* __restrict__ b2,
    const float* __restrict__ m2, const float* __restrict__ v2,
    float* __restrict__ s1, float* __restrict__ h1, float* __restrict__ s2,
    float* __restrict__ h2) {
  int i = threadIdx.x;
  if (i < 128) {
    float s = g1[i] * rsqrtf(v1[i] + BN_EPS);
    s1[i] = s;
    h1[i] = b1[i] - m1[i] * s;
  } else {
    int j = i - 128;
    float s = g2[j] * rsqrtf(v2[j] + BN_EPS);
    s2[j] = s;
    h2[j] = b2[j] - m2[j] * s;
  }
}

// ---------------- MFMA split-bf16 GEMM, register-blocked ----------------
// Wave owns R=4 row-tiles (64 rows); block = 4 waves = 256 rows. Outer loop
// over column tiles: B-frags loaded once into VGPRs, reused by 4 row-tiles
// (6 MFMA per 16B B-load). AIN=1: A pre-split bf16 hi/lo planes (from k_agg);
// AIN=0: fp32 X, split in-kernel. DINV: scale rows by dinv. OUTH: fp16 out.
// GATE: gate[row]=relu(D+gbias).Wg2+bg2, no Y write.
template <int K, int M, int AIN, int DINV, int GATE, int OUTH>
__global__ __launch_bounds__(256, 2) void k_mgemm(
    const float* __restrict__ Xf, const short* __restrict__ Xhi,
    const short* __restrict__ Xlo, const short* __restrict__ Wthi,
    const short* __restrict__ Wtlo, const float* __restrict__ dinv,
    const float* __restrict__ gbias, const float* __restrict__ Wg2v,
    const float* __restrict__ bg2v, void* __restrict__ Y,
    float* __restrict__ gate, int nrows) {
  constexpr int NC = K / 32;  // k chunks of 32
  constexpr int CT = M / 16;  // 16-col tiles
  constexpr int R = 4;        // row tiles per wave
  const int lane = threadIdx.x & 63;
  const int wave = threadIdx.x >> 6;
  const int m16 = lane & 15;
  const int quad = lane >> 4;
  const int rowbase = blockIdx.x * 256 + wave * 64;

  // ---- A fragments for R row-tiles ----
  bf16x8 ahi[R][NC], alo[R][NC];
#pragma unroll
  for (int t = 0; t < R; ++t) {
    const int arow = rowbase + t * 16 + m16;
    const bool rok = arow < nrows;
#pragma unroll
    for (int c = 0; c < NC; ++c) {
      const int k0 = c * 32 + quad * 8;
      if constexpr (AIN) {
        if (rok) {
          ahi[t][c] = *(const bf16x8*)(Xhi + (size_t)arow * K + k0);
          alo[t][c] = *(const bf16x8*)(Xlo + (size_t)arow * K + k0);
        } else {
          ahi[t][c] = bf16x8{0, 0, 0, 0, 0, 0, 0, 0};
          alo[t][c] = bf16x8{0, 0, 0, 0, 0, 0, 0, 0};
        }
      } else {
        float4 v0 = make_float4(0.f, 0.f, 0.f, 0.f), v1 = v0;
        if (rok) {
          v0 = *(const float4*)(Xf + (size_t)arow * K + k0);
          v1 = *(const float4*)(Xf + (size_t)arow * K + k0 + 4);
        }
        float vv[8] = {v0.x, v0.y, v0.z, v0.w, v1.x, v1.y, v1.z, v1.w};
#pragma unroll
        for (int j = 0; j < 8; ++j) {
          short h = f2bf(vv[j]);
          ahi[t][c][j] = h;
          alo[t][c][j] = f2bf(vv[j] - bf2f(h));
        }
      }
    }
  }

  // per-output-row dinv preload
  float dv[R][4];
  if constexpr (DINV && !GATE) {
#pragma unroll
    for (int t = 0; t < R; ++t)
#pragma unroll
      for (int r = 0; r < 4; ++r) {
        int row = rowbase + t * 16 + quad * 4 + r;
        dv[t][r] = (row < nrows) ? dinv[row] : 0.f;
      }
  }

  float gp[R][4];
  if constexpr (GATE) {
#pragma unroll
    for (int t = 0; t < R; ++t)
#pragma unroll
      for (int r = 0; r < 4; ++r) gp[t][r] = 0.f;
  }

#pragma unroll
  for (int ct = 0; ct < CT; ++ct) {
    // B-frags once per ct, reused by R row tiles
    bf16x8 bhi[NC], blo[NC];
    const size_t wrow = (size_t)(ct * 16 + m16) * K + quad * 8;
#pragma unroll
    for (int c = 0; c < NC; ++c) {
      bhi[c] = *(const bf16x8*)(Wthi + wrow + c * 32);
      blo[c] = *(const bf16x8*)(Wtlo + wrow + c * 32);
    }
#pragma unroll
    for (int t = 0; t < R; ++t) {
      f32x4 acc = {0.f, 0.f, 0.f, 0.f};
#pragma unroll
      for (int c = 0; c < NC; ++c) {
        acc = __builtin_amdgcn_mfma_f32_16x16x32_bf16(ahi[t][c], bhi[c], acc, 0, 0, 0);
        acc = __builtin_amdgcn_mfma_f32_16x16x32_bf16(ahi[t][c], blo[c], acc, 0, 0, 0);
        acc = __builtin_amdgcn_mfma_f32_16x16x32_bf16(alo[t][c], bhi[c], acc, 0, 0, 0);
      }
      if constexpr (GATE) {
        const int col = ct * 16 + m16;
        const float gb = gbias[col], wg = Wg2v[col];
#pragma unroll
        for (int r = 0; r < 4; ++r) gp[t][r] += fmaxf(acc[r] + gb, 0.f) * wg;
      } else {
#pragma unroll
        for (int r = 0; r < 4; ++r) {
          const int row = rowbase + t * 16 + quad * 4 + r;
          if (row < nrows) {
            float v = acc[r];
            if constexpr (DINV) v *= dv[t][r];
            if constexpr (OUTH)
              ((__half*)Y)[(size_t)row * M + ct * 16 + m16] = __float2half(v);
            else
              ((float*)Y)[(size_t)row * M + ct * 16 + m16] = v;
          }
        }
      }
    }
  }
  if constexpr (GATE) {
#pragma unroll
    for (int o = 1; o < 16; o <<= 1) {
#pragma unroll
      for (int t = 0; t < R; ++t)
#pragma unroll
        for (int r = 0; r < 4; ++r) gp[t][r] += __shfl_xor(gp[t][r], o, 64);
    }
    if (m16 == 0) {
      const float b2 = bg2v[0];
#pragma unroll
      for (int t = 0; t < R; ++t)
#pragma unroll
        for (int r = 0; r < 4; ++r) {
          const int row = rowbase + t * 16 + quad * 4 + r;
          if (row < nrows) gate[row] = gp[t][r] + b2;
        }
    }
  }
}

// ---------------- GCN aggregation (gather over CSR by dst, fp16 rows) -------
// hp fp16 (pre-scaled by dinv). EPI=0: out fp32 = acc*di + bias.
// EPI=1 (M=128): additionally apply BN+relu and emit pre-split bf16 hi/lo
// planes (next GEMM's A-fragments) instead of fp32.
__device__ inline void acc_h4(float4& a, uint2 u) {
  __half2 h0 = *(__half2*)&u.x;
  __half2 h1 = *(__half2*)&u.y;
  float2 f0 = __half22float2(h0), f1 = __half22float2(h1);
  a.x += f0.x;
  a.y += f0.y;
  a.z += f1.x;
  a.w += f1.y;
}
__device__ inline void acc_h2(float2& a, unsigned u) {
  float2 f = __half22float2(*(__half2*)&u);
  a.x += f.x;
  a.y += f.y;
}

template <int M, int EPI>
__global__ __launch_bounds__(256) void k_agg(const __half* __restrict__ hp,
                                             const int* __restrict__ rowstart,
                                             const int* __restrict__ eidx,
                                             const float* __restrict__ dinv,
                                             const float* __restrict__ bias,
                                             const float* __restrict__ bns,
                                             const float* __restrict__ bnh,
                                             float* __restrict__ outf,
                                             short* __restrict__ ohi,
                                             short* __restrict__ olo, int N) {
  int w = (blockIdx.x * 256 + threadIdx.x) >> 6;  // wave = node
  int lane = threadIdx.x & 63;
  int half_ = lane >> 5;
  int sub = lane & 31;
  if (w >= N) return;
  float di = dinv[w];
  int lo = rowstart[w], hi = rowstart[w + 1];
  if constexpr (M == 128) {
    float4 acc = make_float4(0.f, 0.f, 0.f, 0.f);
    int e = lo + half_;
    for (; e + 6 < hi; e += 8) {  // 4 rows in flight per half-wave
      int s0 = eidx[e], s1 = eidx[e + 2], s2 = eidx[e + 4], s3 = eidx[e + 6];
      uint2 u0 = *(const uint2*)(hp + (size_t)s0 * 128 + sub * 4);
      uint2 u1 = *(const uint2*)(hp + (size_t)s1 * 128 + sub * 4);
      uint2 u2 = *(const uint2*)(hp + (size_t)s2 * 128 + sub * 4);
      uint2 u3 = *(const uint2*)(hp + (size_t)s3 * 128 + sub * 4);
      acc_h4(acc, u0);
      acc_h4(acc, u1);
      acc_h4(acc, u2);
      acc_h4(acc, u3);
    }
    for (; e < hi; e += 2) {
      uint2 u = *(const uint2*)(hp + (size_t)eidx[e] * 128 + sub * 4);
      acc_h4(acc, u);
    }
    acc.x += __shfl_xor(acc.x, 32, 64);
    acc.y += __shfl_xor(acc.y, 32, 64);
    acc.z += __shfl_xor(acc.z, 32, 64);
    acc.w += __shfl_xor(acc.w, 32, 64);
    if (half_ == 0) {
      float4 self = make_float4(0.f, 0.f, 0.f, 0.f);
      acc_h4(self, *(const uint2*)(hp + (size_t)w * 128 + sub * 4));
      float4 bb = *(const float4*)(bias + sub * 4);
      float4 r;
      r.x = (acc.x + self.x) * di + bb.x;
      r.y = (acc.y + self.y) * di + bb.y;
      r.z = (acc.z + self.z) * di + bb.z;
      r.w = (acc.w + self.w) * di + bb.w;
      if constexpr (EPI) {
        float4 s4 = *(const float4*)(bns + sub * 4);
        float4 h4 = *(const float4*)(bnh + sub * 4);
        float e0 = fmaxf(r.x * s4.x + h4.x, 0.f);
        float e1 = fmaxf(r.y * s4.y + h4.y, 0.f);
        float e2 = fmaxf(r.z * s4.z + h4.z, 0.f);
        float e3 = fmaxf(r.w * s4.w + h4.w, 0.f);
        short h0 = f2bf(e0), h1 = f2bf(e1), h2 = f2bf(e2), h3 = f2bf(e3);
        short4 vh = make_short4(h0, h1, h2, h3);
        short4 vl = make_short4(f2bf(e0 - bf2f(h0)), f2bf(e1 - bf2f(h1)),
                                f2bf(e2 - bf2f(h2)), f2bf(e3 - bf2f(h3)));
        *(short4*)(ohi + (size_t)w * 128 + sub * 4) = vh;
        *(short4*)(olo + (size_t)w * 128 + sub * 4) = vl;
      } else {
        *(float4*)(outf + (size_t)w * 128 + sub * 4) = r;
      }
    }
  } else {
    float2 acc = make_float2(0.f, 0.f);
    int e = lo + half_;
    for (; e + 6 < hi; e += 8) {
      int s0 = eidx[e], s1 = eidx[e + 2], s2 = eidx[e + 4], s3 = eidx[e + 6];
      unsigned u0 = *(const unsigned*)(hp + (size_t)s0 * 64 + sub * 2);
      unsigned u1 = *(const unsigned*)(hp + (size_t)s1 * 64 + sub * 2);
      unsigned u2 = *(const unsigned*)(hp + (size_t)s2 * 64 + sub * 2);
      unsigned u3 = *(const unsigned*)(hp + (size_t)s3 * 64 + sub * 2);
      acc_h2(acc, u0);
      acc_h2(acc, u1);
      acc_h2(acc, u2);
      acc_h2(acc, u3);
    }
    for (; e < hi; e += 2) {
      unsigned u = *(const unsigned*)(hp + (size_t)eidx[e] * 64 + sub * 2);
      acc_h2(acc, u);
    }
    acc.x += __shfl_xor(acc.x, 32, 64);
    acc.y += __shfl_xor(acc.y, 32, 64);
    if (half_ == 0) {
      float2 self = make_float2(0.f, 0.f);
      acc_h2(self, *(const unsigned*)(hp + (size_t)w * 64 + sub * 2));
      float2 bb = *(const float2*)(bias + sub * 2);
      float2 r;
      r.x = (acc.x + self.x) * di + bb.x;
      r.y = (acc.y + self.y) * di + bb.y;
      *(float2*)(outf + (size_t)w * 64 + sub * 2) = r;
    }
  }
}

// ---------------- pooling, parallel decomposition ----------------
__global__ __launch_bounds__(128) void k_gbounds(const int* __restrict__ batch,
                                                 int* __restrict__ gstart,
                                                 int N) {
  int g = threadIdx.x;
  if (g > GG) return;
  int lo = 0, hi = N;
  while (lo < hi) {
    int mid = (lo + hi) >> 1;
    if (batch[mid] < g) lo = mid + 1;
    else hi = mid;
  }
  gstart[g] = lo;
}

// chunked max over contiguous per-graph ranges: ONE atomicMax per block
__global__ __launch_bounds__(256) void k_pmax(const float* __restrict__ gate,
                                              const int* __restrict__ gstart,
                                              unsigned* __restrict__ gmaxu) {
  __shared__ unsigned red[256];
  const int g = blockIdx.x / CPB;
  const int c = blockIdx.x % CPB;
  const int lo = gstart[g], hi = gstart[g + 1];
  const int len = hi - lo;
  const int b0 = lo + (int)(((long long)len * c) / CPB);
  const int b1 = lo + (int)(((long long)len * (c + 1)) / CPB);
  unsigned mx = 0u;
  for (int i = b0 + threadIdx.x; i < b1; i += 256) mx = max(mx, fenc(gate[i]));
  red[threadIdx.x] = mx;
  __syncthreads();
  for (int o = 128; o; o >>= 1) {
    if (threadIdx.x < o)
      red[threadIdx.x] = max(red[threadIdx.x], red[threadIdx.x + o]);
    __syncthreads();
  }
  if (threadIdx.x == 0 && red[0] != 0u) atomicMax(&gmaxu[g], red[0]);
}

// grid = GG*CPB blocks, 256 thr (4 waves). lane=feature, wave strides nodes.
__global__ __launch_bounds__(256) void k_psum(const float* __restrict__ gate,
                                              const float* __restrict__ h3,
                                              const unsigned* __restrict__ gmaxu,
                                              const int* __restrict__ gstart,
                                              float* __restrict__ pooledw,
                                              float* __restrict__ ssum) {
  __shared__ float accs[4][64];
  __shared__ float ses[4];
  const int g = blockIdx.x / CPB;
  const int c = blockIdx.x % CPB;
  const int lo = gstart[g], hi = gstart[g + 1];
  const int len = hi - lo;
  const int b0 = lo + (int)(((long long)len * c) / CPB);
  const int b1 = lo + (int)(((long long)len * (c + 1)) / CPB);
  const int wave = threadIdx.x >> 6, lane = threadIdx.x & 63;
  const float m = fdec(gmaxu[g]);
  float acc = 0.f, se = 0.f;
  for (int i = b0 + wave; i < b1; i += 4) {
    float e = expf(gate[i] - m);
    acc += e * h3[(size_t)i * 64 + lane];
    se += e;
  }
  accs[wave][lane] = acc;
  if (lane == 0) ses[wave] = se;
  __syncthreads();
  if (threadIdx.x < 64) {
    float a = accs[0][threadIdx.x] + accs[1][threadIdx.x] +
              accs[2][threadIdx.x] + accs[3][threadIdx.x];
    if (a != 0.f) atomicAdd(&pooledw[g * 64 + threadIdx.x], a);
  }
  if (threadIdx.x == 64) {
    float s = ses[0] + ses[1] + ses[2] + ses[3];
    if (s != 0.f) atomicAdd(&ssum[g], s);
  }
}

// ---------------- head MLP (single block); normalization fused into P load --
__global__ __launch_bounds__(256) void k_head(const float* __restrict__ pooledw,
                                              const float* __restrict__ ssum,
                                              const float* __restrict__ Wm1,
                                              const float* __restrict__ bm1,
                                              const float* __restrict__ Wm2,
                                              const float* __restrict__ bm2,
                                              float* __restrict__ out) {
  __shared__ float P[64 * 64];
  __shared__ float T[64 * 128];
  int tid = threadIdx.x;
  for (int i = tid; i < 4096; i += 256) {
    float s = ssum[i >> 6];
    P[i] = pooledw[i] * ((s > 0.f) ? 1.0f / s : 0.f);
  }
  __syncthreads();
  for (int e = tid; e < 8192; e += 256) {
    int r = e >> 7, c = e & 127;
    float a = bm1[c];
    for (int k = 0; k < 64; ++k) a += P[r * 64 + k] * Wm1[k * 128 + c];
    T[e] = fmaxf(a, 0.f);
  }
  __syncthreads();
  for (int e = tid; e < 4096; e += 256) {
    int r = e >> 6, c = e & 63;
    float a = bm2[c];
    for (int k = 0; k < 128; ++k) a += T[r * 128 + k] * Wm2[k * 64 + c];
    out[e] = a;
  }
}

extern "C" void kernel_launch(void* const* d_in, const int* in_sizes, int n_in,
                              void* d_out, int out_size, void* d_ws,
                              size_t ws_size, hipStream_t stream) {
  const int N = NN, E = EE;
  const float* x = (const float*)d_in[0];
  const int* ei = (const int*)d_in[1];
  const int* batch = (const int*)d_in[2];
  const float* W1 = (const float*)d_in[3];
  const float* b1 = (const float*)d_in[4];
  const float* W2 = (const float*)d_in[5];
  const float* b2 = (const float*)d_in[6];
  const float* W3 = (const float*)d_in[7];
  const float* b3 = (const float*)d_in[8];
  const float* g1 = (const float*)d_in[9];
  const float* beta1 = (const float*)d_in[10];
  const float* g2 = (const float*)d_in[11];
  const float* beta2 = (const float*)d_in[12];
  const float* mean1 = (const float*)d_in[13];
  const float* var1 = (const float*)d_in[14];
  const float* mean2 = (const float*)d_in[15];
  const float* var2 = (const float*)d_in[16];
  const float* Wg1 = (const float*)d_in[17];
  const float* bg1 = (const float*)d_in[18];
  const float* Wg2 = (const float*)d_in[19];
  const float* bg2 = (const float*)d_in[20];
  const float* Wm1 = (const float*)d_in[21];
  const float* bm1 = (const float*)d_in[22];
  const float* Wm2 = (const float*)d_in[23];
  const float* bm2 = (const float*)d_in[24];
  float* out = (float*)d_out;

  const int* src = ei;
  const int* dst = ei + E;

  char* wsb = (char*)d_ws;
  size_t off = 0;
  auto alloc = [&](size_t elems) -> void* {
    void* p = wsb + off;
    off += elems * 4;
    return p;
  };
  int* cnt = (int*)alloc(N);
  int* rowstart = (int*)alloc(N + 4);
  int* cursor = (int*)alloc(N);
  int* eidx = (int*)alloc(E);
  float* dinv = (float*)alloc(N);
  float* gate = (float*)alloc(N);
  __half* hbuf = (__half*)alloc((size_t)N * 64);  // fp16 N x 128 plane
  short* ahi_p = (short*)alloc((size_t)N * 64);   // bf16-hi N x 128 plane
  short* alo_p = (short*)alloc((size_t)N * 64);   // bf16-lo N x 128 plane
  float* fbuf = (float*)alloc((size_t)N * 64);    // fp32 N x 64 (h3)
  int* bsum = (int*)alloc(256);
  int* boff = (int*)alloc(256);
  short* wt = (short*)alloc(49152);  // 98304 shorts
  float* bn1s = (float*)alloc(128);
  float* bn1h = (float*)alloc(128);
  float* bn2s = (float*)alloc(128);
  float* bn2h = (float*)alloc(128);
  // pooling buffers (contiguous for one memset): pooledw + ssum + gmaxu
  float* pooledw = (float*)alloc(GG * 64);
  float* ssum = (float*)alloc(GG);
  unsigned* gmaxu = (unsigned*)alloc(GG);
  int* gstart = (int*)alloc(GG + 4);
  (void)ws_size;
  (void)n_in;
  (void)in_sizes;
  (void)out_size;

  const int nscan = (N + SB - 1) / SB;

  // CSR build (once, reused for all 3 conv layers)
  hipMemsetAsync(cnt, 0, N * sizeof(int), stream);
  hipMemsetAsync(pooledw, 0, (GG * 64 + GG + GG) * sizeof(float), stream);
  k_count<<<(E + 255) / 256, 256, 0, stream>>>(dst, cnt, E);
  k_scan1<<<nscan, SB, 0, stream>>>(cnt, dinv, bsum, N);
  k_scan2<<<1, 256, 0, stream>>>(bsum, boff, nscan, rowstart + N);
  k_scan3<<<nscan, SB, 0, stream>>>(cnt, boff, rowstart, cursor, N);
  k_fill<<<(E + 255) / 256, 256, 0, stream>>>(src, dst, cursor, eidx, E);

  // weight/bn prep + graph bounds
  k_wsplit<<<192, 256, 0, stream>>>(W1, W2, W3, Wg1, wt);
  k_bnprep<<<1, 256, 0, stream>>>(g1, beta1, mean1, var1, g2, beta2, mean2,
                                  var2, bn1s, bn1h, bn2s, bn2h);
  k_gbounds<<<1, 128, 0, stream>>>(batch, gstart, N);

  const int gb = (N + 255) / 256;       // GEMM blocks (256 rows each)
  const int ab = (N * 64 + 255) / 256;  // agg blocks (wave per node)

  // Layer 1: hp1 = fp16((x@W1)*dinv) ; agg -> BN1+relu -> split planes
  k_mgemm<128, 128, 0, 1, 0, 1><<<gb, 256, 0, stream>>>(
      x, nullptr, nullptr, wt, wt + 16384, dinv, nullptr, nullptr, nullptr,
      hbuf, nullptr, N);
  k_agg<128, 1><<<ab, 256, 0, stream>>>(hbuf, rowstart, eidx, dinv, b1, bn1s,
                                        bn1h, nullptr, ahi_p, alo_p, N);

  // Layer 2: A from pre-split planes
  k_mgemm<128, 128, 1, 1, 0, 1><<<gb, 256, 0, stream>>>(
      nullptr, ahi_p, alo_p, wt + 32768, wt + 49152, dinv, nullptr, nullptr,
      nullptr, hbuf, nullptr, N);
  k_agg<128, 1><<<ab, 256, 0, stream>>>(hbuf, rowstart, eidx, dinv, b2, bn2s,
                                        bn2h, nullptr, ahi_p, alo_p, N);

  // Layer 3 (M=64): A from planes; agg -> h3 fp32
  k_mgemm<128, 64, 1, 1, 0, 1><<<gb, 256, 0, stream>>>(
      nullptr, ahi_p, alo_p, wt + 65536, wt + 73728, dinv, nullptr, nullptr,
      nullptr, hbuf, nullptr, N);
  k_agg<64, 0><<<ab, 256, 0, stream>>>(hbuf, rowstart, eidx, dinv, b3, nullptr,
                                       nullptr, fbuf, nullptr, nullptr, N);
  // h3 = fbuf (N x 64, fp32)

  // gate = relu(h3@Wg1+bg1)@Wg2+bg2 (fused epilogue)
  k_mgemm<64, 128, 0, 0, 1, 0><<<gb, 256, 0, stream>>>(
      fbuf, nullptr, nullptr, wt + 81920, wt + 90112, nullptr, bg1, Wg2, bg2,
      nullptr, gate, N);

  // softmax pooling (parallel): chunked max -> exp-sums -> (normalize in head)
  k_pmax<<<GG * CPB, 256, 0, stream>>>(gate, gstart, gmaxu);
  k_psum<<<GG * CPB, 256, 0, stream>>>(gate, fbuf, gmaxu, gstart, pooledw,
                                       ssum);

  // head MLP
  k_head<<<1, 256, 0, stream>>>(pooledw, ssum, Wm1, bm1, Wm2, bm2, out);
}

// Round 10
// 572.479 us; speedup vs baseline: 2.0599x; 1.0015x over previous
//
#include <hip/hip_runtime.h>
#include <hip/hip_bf16.h>
#include <hip/hip_fp16.h>
#include <math.h>

#define NN 100000
#define EE 1000000
#define GG 64
#define BN_EPS 1e-5f
#define SB 512   // scan block size
#define CPB 16   // pooling chunks per graph
#define EB 4096  // edges per bucket-pass block
#define NBLK ((EE + EB - 1) / EB)  // 245

typedef __attribute__((ext_vector_type(8))) short bf16x8;
typedef __attribute__((ext_vector_type(4))) float f32x4;

// float -> bf16 (RNE) and back, as raw shorts
__device__ inline short f2bf(float f) {
  unsigned u = __float_as_uint(f);
  u = u + 0x7fff + ((u >> 16) & 1);
  return (short)(u >> 16);
}
__device__ inline float bf2f(short h) {
  return __uint_as_float(((unsigned)(unsigned short)h) << 16);
}

// order-preserving float<->uint transform (for atomicMax on floats)
__device__ inline unsigned fenc(float f) {
  int b = __float_as_int(f);
  return (b < 0) ? ~(unsigned)b : ((unsigned)b | 0x80000000u);
}
__device__ inline float fdec(unsigned u) {
  int b = (u & 0x80000000u) ? (int)(u & 0x7fffffffu) : (int)~u;
  return __int_as_float(b);
}

// ---------------- degree count ----------------
__global__ __launch_bounds__(256) void k_count(const int* __restrict__ dst,
                                               int* __restrict__ cnt, int E) {
  int i = blockIdx.x * 256 + threadIdx.x;
  if (i < E) atomicAdd(&cnt[dst[i]], 1);
}

// ---------------- hierarchical scan (rowstart over cnt) ----------------
__global__ __launch_bounds__(SB) void k_scan1(const int* __restrict__ cnt,
                                              float* __restrict__ dinv,
                                              int* __restrict__ bsum, int N) {
  __shared__ int red[SB];
  int t = threadIdx.x;
  int i = blockIdx.x * SB + t;
  int v = (i < N) ? cnt[i] : 0;
  if (i < N) dinv[i] = rsqrtf(1.0f + (float)v);
  red[t] = v;
  __syncthreads();
  for (int o = SB / 2; o; o >>= 1) {
    if (t < o) red[t] += red[t + o];
    __syncthreads();
  }
  if (t == 0) bsum[blockIdx.x] = red[0];
}

__global__ __launch_bounds__(256) void k_scan2(const int* __restrict__ bsum,
                                               int* __restrict__ boff, int nb,
                                               int* __restrict__ total_out) {
  __shared__ int s[256];
  int t = threadIdx.x;
  int v = (t < nb) ? bsum[t] : 0;
  s[t] = v;
  __syncthreads();
  for (int o = 1; o < 256; o <<= 1) {
    int u = (t >= o) ? s[t - o] : 0;
    __syncthreads();
    s[t] += u;
    __syncthreads();
  }
  boff[t] = s[t] - v;  // exclusive
  if (t == 255) *total_out = s[255];
}

__global__ __launch_bounds__(SB) void k_scan3(const int* __restrict__ cnt,
                                              const int* __restrict__ boff,
                                              int* __restrict__ rowstart,
                                              int* __restrict__ cursor, int N) {
  __shared__ int s[SB];
  int t = threadIdx.x;
  int i = blockIdx.x * SB + t;
  int v = (i < N) ? cnt[i] : 0;
  s[t] = v;
  __syncthreads();
  for (int o = 1; o < SB; o <<= 1) {
    int u = (t >= o) ? s[t - o] : 0;
    __syncthreads();
    s[t] += u;
    __syncthreads();
  }
  int excl = s[t] - v + boff[blockIdx.x];
  if (i < N) {
    rowstart[i] = excl;
    cursor[i] = excl;
  }
}

// ---------------- bucketed CSR fill (kills scatter write-amplification) -----
// bucket = dst >> 9 (196 buckets of 512 nodes)
__global__ __launch_bounds__(256) void k_bhist(const int* __restrict__ dst,
                                               int* __restrict__ bhist, int E) {
  __shared__ int h[256];
  int t = threadIdx.x;
  h[t] = 0;
  __syncthreads();
  int base = blockIdx.x * EB;
#pragma unroll
  for (int j = 0; j < EB / 256; ++j) {
    int i = base + j * 256 + t;
    if (i < E) atomicAdd(&h[dst[i] >> 9], 1);
  }
  __syncthreads();
  bhist[blockIdx.x * 256 + t] = h[t];
}

// column-exclusive scan over blocks, per bucket (block = bucket)
__global__ __launch_bounds__(256) void k_bscan1(int* __restrict__ bhist,
                                                int* __restrict__ btot) {
  __shared__ int s[256];
  int bin = blockIdx.x, t = threadIdx.x;
  int v = (t < NBLK) ? bhist[t * 256 + bin] : 0;
  s[t] = v;
  __syncthreads();
  for (int o = 1; o < 256; o <<= 1) {
    int u = (t >= o) ? s[t - o] : 0;
    __syncthreads();
    s[t] += u;
    __syncthreads();
  }
  if (t < NBLK) bhist[t * 256 + bin] = s[t] - v;  // exclusive within column
  if (t == 255) btot[bin] = s[255];
}

__global__ __launch_bounds__(256) void k_bscan2(const int* __restrict__ btot,
                                                int* __restrict__ bstart) {
  __shared__ int s[256];
  int t = threadIdx.x;
  int v = btot[t];
  s[t] = v;
  __syncthreads();
  for (int o = 1; o < 256; o <<= 1) {
    int u = (t >= o) ? s[t - o] : 0;
    __syncthreads();
    s[t] += u;
    __syncthreads();
  }
  bstart[t] = s[t] - v;
}

// scatter (src,dst) pairs into bucket-grouped order
__global__ __launch_bounds__(256) void k_bscat(const int* __restrict__ src,
                                               const int* __restrict__ dst,
                                               const int* __restrict__ bhist,
                                               const int* __restrict__ bstart,
                                               int2* __restrict__ pairs, int E) {
  __shared__ int h[256];
  __shared__ int base[256];
  int t = threadIdx.x;
  h[t] = 0;
  __syncthreads();
  int b0 = blockIdx.x * EB;
  int ds[EB / 256], rk[EB / 256];
#pragma unroll
  for (int j = 0; j < EB / 256; ++j) {
    int i = b0 + j * 256 + t;
    if (i < E) {
      int d = dst[i];
      ds[j] = d;
      rk[j] = atomicAdd(&h[d >> 9], 1);
    } else
      ds[j] = -1;
  }
  __syncthreads();
  base[t] = bstart[t] + bhist[blockIdx.x * 256 + t];
  __syncthreads();
#pragma unroll
  for (int j = 0; j < EB / 256; ++j) {
    int i = b0 + j * 256 + t;
    if (ds[j] >= 0) {
      int pos = base[ds[j] >> 9] + rk[j];
      pairs[pos] = make_int2(src[i], ds[j]);
    }
  }
}

// final fill from bucket-grouped pairs: cursor/eidx writes are L2-local
__global__ __launch_bounds__(256) void k_fill2(const int2* __restrict__ pairs,
                                               int* __restrict__ cursor,
                                               int* __restrict__ eidx, int E) {
  int b0 = blockIdx.x * 1024;
#pragma unroll
  for (int j = 0; j < 4; ++j) {
    int i = b0 + j * 256 + threadIdx.x;
    if (i < E) {
      int2 p = pairs[i];
      int pos = atomicAdd(&cursor[p.y], 1);
      eidx[pos] = p.x;
    }
  }
}

// ---------------- weight prep: transpose + split into bf16 hi/lo ------------
__global__ __launch_bounds__(256) void k_wsplit(const float* __restrict__ W1,
                                                const float* __restrict__ W2,
                                                const float* __restrict__ W3,
                                                const float* __restrict__ Wg1,
                                                short* __restrict__ wt) {
  int i = blockIdx.x * 256 + threadIdx.x;
  const float* W;
  short *hi, *lo;
  int K, M, idx;
  if (i < 16384) {
    W = W1; hi = wt; lo = wt + 16384; K = 128; M = 128; idx = i;
  } else if (i < 32768) {
    W = W2; hi = wt + 32768; lo = wt + 49152; K = 128; M = 128; idx = i - 16384;
  } else if (i < 40960) {
    W = W3; hi = wt + 65536; lo = wt + 73728; K = 128; M = 64; idx = i - 32768;
  } else {
    W = Wg1; hi = wt + 81920; lo = wt + 90112; K = 64; M = 128; idx = i - 40960;
  }
  int k = idx / M, n = idx % M;
  float w = W[idx];
  short h = f2bf(w);
  hi[n * K + k] = h;
  lo[n * K + k] = f2bf(w - bf2f(h));
}

// ---------------- BN prep ----------------
__global__ __launch_bounds__(256) void k_bnprep(
    const float* __restrict__ g1, const float* __restrict__ b1,
    const float* __restrict__ m1, const float* __restrict__ v1,
    const float* __restrict__ g2, const float* __restrict__ b2,
    const float* __restrict__ m2, const float* __restrict__ v2,
    float* __restrict__ s1, float* __restrict__ h1, float* __restrict__ s2,
    float* __restrict__ h2) {
  int i = threadIdx.x;
  if (i < 128) {
    float s = g1[i] * rsqrtf(v1[i] + BN_EPS);
    s1[i] = s;
    h1[i] = b1[i] - m1[i] * s;
  } else {
    int j = i - 128;
    float s = g2[j] * rsqrtf(v2[j] + BN_EPS);
    s2[j] = s;
    h2[j] = b2[j] - m2[j] * s;
  }
}

// ---------------- MFMA split-bf16 GEMM, register-blocked ----------------
template <int K, int M, int AIN, int DINV, int GATE, int OUTH>
__global__ __launch_bounds__(256, 2) void k_mgemm(
    const float* __restrict__ Xf, const short* __restrict__ Xhi,
    const short* __restrict__ Xlo, const short* __restrict__ Wthi,
    const short* __restrict__ Wtlo, const float* __restrict__ dinv,
    const float* __restrict__ gbias, const float* __restrict__ Wg2v,
    const float* __restrict__ bg2v, void* __restrict__ Y,
    float* __restrict__ gate, int nrows) {
  constexpr int NC = K / 32;  // k chunks of 32
  constexpr int CT = M / 16;  // 16-col tiles
  constexpr int R = 4;        // row tiles per wave
  const int lane = threadIdx.x & 63;
  const int wave = threadIdx.x >> 6;
  const int m16 = lane & 15;
  const int quad = lane >> 4;
  const int rowbase = blockIdx.x * 256 + wave * 64;

  bf16x8 ahi[R][NC], alo[R][NC];
#pragma unroll
  for (int t = 0; t < R; ++t) {
    const int arow = rowbase + t * 16 + m16;
    const bool rok = arow < nrows;
#pragma unroll
    for (int c = 0; c < NC; ++c) {
      const int k0 = c * 32 + quad * 8;
      if constexpr (AIN) {
        if (rok) {
          ahi[t][c] = *(const bf16x8*)(Xhi + (size_t)arow * K + k0);
          alo[t][c] = *(const bf16x8*)(Xlo + (size_t)arow * K + k0);
        } else {
          ahi[t][c] = bf16x8{0, 0, 0, 0, 0, 0, 0, 0};
          alo[t][c] = bf16x8{0, 0, 0, 0, 0, 0, 0, 0};
        }
      } else {
        float4 v0 = make_float4(0.f, 0.f, 0.f, 0.f), v1 = v0;
        if (rok) {
          v0 = *(const float4*)(Xf + (size_t)arow * K + k0);
          v1 = *(const float4*)(Xf + (size_t)arow * K + k0 + 4);
        }
        float vv[8] = {v0.x, v0.y, v0.z, v0.w, v1.x, v1.y, v1.z, v1.w};
#pragma unroll
        for (int j = 0; j < 8; ++j) {
          short h = f2bf(vv[j]);
          ahi[t][c][j] = h;
          alo[t][c][j] = f2bf(vv[j] - bf2f(h));
        }
      }
    }
  }

  float dv[R][4];
  if constexpr (DINV && !GATE) {
#pragma unroll
    for (int t = 0; t < R; ++t)
#pragma unroll
      for (int r = 0; r < 4; ++r) {
        int row = rowbase + t * 16 + quad * 4 + r;
        dv[t][r] = (row < nrows) ? dinv[row] : 0.f;
      }
  }

  float gp[R][4];
  if constexpr (GATE) {
#pragma unroll
    for (int t = 0; t < R; ++t)
#pragma unroll
      for (int r = 0; r < 4; ++r) gp[t][r] = 0.f;
  }

#pragma unroll
  for (int ct = 0; ct < CT; ++ct) {
    bf16x8 bhi[NC], blo[NC];
    const size_t wrow = (size_t)(ct * 16 + m16) * K + quad * 8;
#pragma unroll
    for (int c = 0; c < NC; ++c) {
      bhi[c] = *(const bf16x8*)(Wthi + wrow + c * 32);
      blo[c] = *(const bf16x8*)(Wtlo + wrow + c * 32);
    }
#pragma unroll
    for (int t = 0; t < R; ++t) {
      f32x4 acc = {0.f, 0.f, 0.f, 0.f};
#pragma unroll
      for (int c = 0; c < NC; ++c) {
        acc = __builtin_amdgcn_mfma_f32_16x16x32_bf16(ahi[t][c], bhi[c], acc, 0, 0, 0);
        acc = __builtin_amdgcn_mfma_f32_16x16x32_bf16(ahi[t][c], blo[c], acc, 0, 0, 0);
        acc = __builtin_amdgcn_mfma_f32_16x16x32_bf16(alo[t][c], bhi[c], acc, 0, 0, 0);
      }
      if constexpr (GATE) {
        const int col = ct * 16 + m16;
        const float gb = gbias[col], wg = Wg2v[col];
#pragma unroll
        for (int r = 0; r < 4; ++r) gp[t][r] += fmaxf(acc[r] + gb, 0.f) * wg;
      } else {
#pragma unroll
        for (int r = 0; r < 4; ++r) {
          const int row = rowbase + t * 16 + quad * 4 + r;
          if (row < nrows) {
            float v = acc[r];
            if constexpr (DINV) v *= dv[t][r];
            if constexpr (OUTH)
              ((__half*)Y)[(size_t)row * M + ct * 16 + m16] = __float2half(v);
            else
              ((float*)Y)[(size_t)row * M + ct * 16 + m16] = v;
          }
        }
      }
    }
  }
  if constexpr (GATE) {
#pragma unroll
    for (int o = 1; o < 16; o <<= 1) {
#pragma unroll
      for (int t = 0; t < R; ++t)
#pragma unroll
        for (int r = 0; r < 4; ++r) gp[t][r] += __shfl_xor(gp[t][r], o, 64);
    }
    if (m16 == 0) {
      const float b2 = bg2v[0];
#pragma unroll
      for (int t = 0; t < R; ++t)
#pragma unroll
        for (int r = 0; r < 4; ++r) {
          const int row = rowbase + t * 16 + quad * 4 + r;
          if (row < nrows) gate[row] = gp[t][r] + b2;
        }
    }
  }
}

// ---------------- GCN aggregation (gather over CSR by dst, fp16 rows) -------
__device__ inline void acc_h4(float4& a, uint2 u) {
  __half2 h0 = *(__half2*)&u.x;
  __half2 h1 = *(__half2*)&u.y;
  float2 f0 = __half22float2(h0), f1 = __half22float2(h1);
  a.x += f0.x;
  a.y += f0.y;
  a.z += f1.x;
  a.w += f1.y;
}
__device__ inline void acc_h2(float2& a, unsigned u) {
  float2 f = __half22float2(*(__half2*)&u);
  a.x += f.x;
  a.y += f.y;
}

template <int M, int EPI>
__global__ __launch_bounds__(256) void k_agg(const __half* __restrict__ hp,
                                             const int* __restrict__ rowstart,
                                             const int* __restrict__ eidx,
                                             const float* __restrict__ dinv,
                                             const float* __restrict__ bias,
                                             const float* __restrict__ bns,
                                             const float* __restrict__ bnh,
                                             float* __restrict__ outf,
                                             short* __restrict__ ohi,
                                             short* __restrict__ olo, int N) {
  int w = (blockIdx.x * 256 + threadIdx.x) >> 6;  // wave = node
  int lane = threadIdx.x & 63;
  int half_ = lane >> 5;
  int sub = lane & 31;
  if (w >= N) return;
  float di = dinv[w];
  int lo = rowstart[w], hi = rowstart[w + 1];
  if constexpr (M == 128) {
    float4 acc = make_float4(0.f, 0.f, 0.f, 0.f);
    int e = lo + half_;
    for (; e + 6 < hi; e += 8) {
      int s0 = eidx[e], s1 = eidx[e + 2], s2 = eidx[e + 4], s3 = eidx[e + 6];
      uint2 u0 = *(const uint2*)(hp + (size_t)s0 * 128 + sub * 4);
      uint2 u1 = *(const uint2*)(hp + (size_t)s1 * 128 + sub * 4);
      uint2 u2 = *(const uint2*)(hp + (size_t)s2 * 128 + sub * 4);
      uint2 u3 = *(const uint2*)(hp + (size_t)s3 * 128 + sub * 4);
      acc_h4(acc, u0);
      acc_h4(acc, u1);
      acc_h4(acc, u2);
      acc_h4(acc, u3);
    }
    for (; e < hi; e += 2) {
      uint2 u = *(const uint2*)(hp + (size_t)eidx[e] * 128 + sub * 4);
      acc_h4(acc, u);
    }
    acc.x += __shfl_xor(acc.x, 32, 64);
    acc.y += __shfl_xor(acc.y, 32, 64);
    acc.z += __shfl_xor(acc.z, 32, 64);
    acc.w += __shfl_xor(acc.w, 32, 64);
    if (half_ == 0) {
      float4 self = make_float4(0.f, 0.f, 0.f, 0.f);
      acc_h4(self, *(const uint2*)(hp + (size_t)w * 128 + sub * 4));
      float4 bb = *(const float4*)(bias + sub * 4);
      float4 r;
      r.x = (acc.x + self.x) * di + bb.x;
      r.y = (acc.y + self.y) * di + bb.y;
      r.z = (acc.z + self.z) * di + bb.z;
      r.w = (acc.w + self.w) * di + bb.w;
      if constexpr (EPI) {
        float4 s4 = *(const float4*)(bns + sub * 4);
        float4 h4 = *(const float4*)(bnh + sub * 4);
        float e0 = fmaxf(r.x * s4.x + h4.x, 0.f);
        float e1 = fmaxf(r.y * s4.y + h4.y, 0.f);
        float e2 = fmaxf(r.z * s4.z + h4.z, 0.f);
        float e3 = fmaxf(r.w * s4.w + h4.w, 0.f);
        short h0 = f2bf(e0), h1 = f2bf(e1), h2 = f2bf(e2), h3 = f2bf(e3);
        short4 vh = make_short4(h0, h1, h2, h3);
        short4 vl = make_short4(f2bf(e0 - bf2f(h0)), f2bf(e1 - bf2f(h1)),
                                f2bf(e2 - bf2f(h2)), f2bf(e3 - bf2f(h3)));
        *(short4*)(ohi + (size_t)w * 128 + sub * 4) = vh;
        *(short4*)(olo + (size_t)w * 128 + sub * 4) = vl;
      } else {
        *(float4*)(outf + (size_t)w * 128 + sub * 4) = r;
      }
    }
  } else {
    float2 acc = make_float2(0.f, 0.f);
    int e = lo + half_;
    for (; e + 6 < hi; e += 8) {
      int s0 = eidx[e], s1 = eidx[e + 2], s2 = eidx[e + 4], s3 = eidx[e + 6];
      unsigned u0 = *(const unsigned*)(hp + (size_t)s0 * 64 + sub * 2);
      unsigned u1 = *(const unsigned*)(hp + (size_t)s1 * 64 + sub * 2);
      unsigned u2 = *(const unsigned*)(hp + (size_t)s2 * 64 + sub * 2);
      unsigned u3 = *(const unsigned*)(hp + (size_t)s3 * 64 + sub * 2);
      acc_h2(acc, u0);
      acc_h2(acc, u1);
      acc_h2(acc, u2);
      acc_h2(acc, u3);
    }
    for (; e < hi; e += 2) {
      unsigned u = *(const unsigned*)(hp + (size_t)eidx[e] * 64 + sub * 2);
      acc_h2(acc, u);
    }
    acc.x += __shfl_xor(acc.x, 32, 64);
    acc.y += __shfl_xor(acc.y, 32, 64);
    if (half_ == 0) {
      float2 self = make_float2(0.f, 0.f);
      acc_h2(self, *(const unsigned*)(hp + (size_t)w * 64 + sub * 2));
      float2 bb = *(const float2*)(bias + sub * 2);
      float2 r;
      r.x = (acc.x + self.x) * di + bb.x;
      r.y = (acc.y + self.y) * di + bb.y;
      *(float2*)(outf + (size_t)w * 64 + sub * 2) = r;
    }
  }
}

// ---------------- pooling, parallel decomposition ----------------
__global__ __launch_bounds__(128) void k_gbounds(const int* __restrict__ batch,
                                                 int* __restrict__ gstart,
                                                 int N) {
  int g = threadIdx.x;
  if (g > GG) return;
  int lo = 0, hi = N;
  while (lo < hi) {
    int mid = (lo + hi) >> 1;
    if (batch[mid] < g) lo = mid + 1;
    else hi = mid;
  }
  gstart[g] = lo;
}

__global__ __launch_bounds__(256) void k_pmax(const float* __restrict__ gate,
                                              const int* __restrict__ gstart,
                                              unsigned* __restrict__ gmaxu) {
  __shared__ unsigned red[256];
  const int g = blockIdx.x / CPB;
  const int c = blockIdx.x % CPB;
  const int lo = gstart[g], hi = gstart[g + 1];
  const int len = hi - lo;
  const int b0 = lo + (int)(((long long)len * c) / CPB);
  const int b1 = lo + (int)(((long long)len * (c + 1)) / CPB);
  unsigned mx = 0u;
  for (int i = b0 + threadIdx.x; i < b1; i += 256) mx = max(mx, fenc(gate[i]));
  red[threadIdx.x] = mx;
  __syncthreads();
  for (int o = 128; o; o >>= 1) {
    if (threadIdx.x < o)
      red[threadIdx.x] = max(red[threadIdx.x], red[threadIdx.x + o]);
    __syncthreads();
  }
  if (threadIdx.x == 0 && red[0] != 0u) atomicMax(&gmaxu[g], red[0]);
}

__global__ __launch_bounds__(256) void k_psum(const float* __restrict__ gate,
                                              const float* __restrict__ h3,
                                              const unsigned* __restrict__ gmaxu,
                                              const int* __restrict__ gstart,
                                              float* __restrict__ pooledw,
                                              float* __restrict__ ssum) {
  __shared__ float accs[4][64];
  __shared__ float ses[4];
  const int g = blockIdx.x / CPB;
  const int c = blockIdx.x % CPB;
  const int lo = gstart[g], hi = gstart[g + 1];
  const int len = hi - lo;
  const int b0 = lo + (int)(((long long)len * c) / CPB);
  const int b1 = lo + (int)(((long long)len * (c + 1)) / CPB);
  const int wave = threadIdx.x >> 6, lane = threadIdx.x & 63;
  const float m = fdec(gmaxu[g]);
  float acc = 0.f, se = 0.f;
  for (int i = b0 + wave; i < b1; i += 4) {
    float e = expf(gate[i] - m);
    acc += e * h3[(size_t)i * 64 + lane];
    se += e;
  }
  accs[wave][lane] = acc;
  if (lane == 0) ses[wave] = se;
  __syncthreads();
  if (threadIdx.x < 64) {
    float a = accs[0][threadIdx.x] + accs[1][threadIdx.x] +
              accs[2][threadIdx.x] + accs[3][threadIdx.x];
    if (a != 0.f) atomicAdd(&pooledw[g * 64 + threadIdx.x], a);
  }
  if (threadIdx.x == 64) {
    float s = ses[0] + ses[1] + ses[2] + ses[3];
    if (s != 0.f) atomicAdd(&ssum[g], s);
  }
}

// ---------------- head MLP ----------------
__global__ __launch_bounds__(256) void k_head(const float* __restrict__ pooledw,
                                              const float* __restrict__ ssum,
                                              const float* __restrict__ Wm1,
                                              const float* __restrict__ bm1,
                                              const float* __restrict__ Wm2,
                                              const float* __restrict__ bm2,
                                              float* __restrict__ out) {
  __shared__ float P[64 * 64];
  __shared__ float T[64 * 128];
  int tid = threadIdx.x;
  for (int i = tid; i < 4096; i += 256) {
    float s = ssum[i >> 6];
    P[i] = pooledw[i] * ((s > 0.f) ? 1.0f / s : 0.f);
  }
  __syncthreads();
  for (int e = tid; e < 8192; e += 256) {
    int r = e >> 7, c = e & 127;
    float a = bm1[c];
    for (int k = 0; k < 64; ++k) a += P[r * 64 + k] * Wm1[k * 128 + c];
    T[e] = fmaxf(a, 0.f);
  }
  __syncthreads();
  for (int e = tid; e < 4096; e += 256) {
    int r = e >> 6, c = e & 63;
    float a = bm2[c];
    for (int k = 0; k < 128; ++k) a += T[r * 128 + k] * Wm2[k * 64 + c];
    out[e] = a;
  }
}

extern "C" void kernel_launch(void* const* d_in, const int* in_sizes, int n_in,
                              void* d_out, int out_size, void* d_ws,
                              size_t ws_size, hipStream_t stream) {
  const int N = NN, E = EE;
  const float* x = (const float*)d_in[0];
  const int* ei = (const int*)d_in[1];
  const int* batch = (const int*)d_in[2];
  const float* W1 = (const float*)d_in[3];
  const float* b1 = (const float*)d_in[4];
  const float* W2 = (const float*)d_in[5];
  const float* b2 = (const float*)d_in[6];
  const float* W3 = (const float*)d_in[7];
  const float* b3 = (const float*)d_in[8];
  const float* g1 = (const float*)d_in[9];
  const float* beta1 = (const float*)d_in[10];
  const float* g2 = (const float*)d_in[11];
  const float* beta2 = (const float*)d_in[12];
  const float* mean1 = (const float*)d_in[13];
  const float* var1 = (const float*)d_in[14];
  const float* mean2 = (const float*)d_in[15];
  const float* var2 = (const float*)d_in[16];
  const float* Wg1 = (const float*)d_in[17];
  const float* bg1 = (const float*)d_in[18];
  const float* Wg2 = (const float*)d_in[19];
  const float* bg2 = (const float*)d_in[20];
  const float* Wm1 = (const float*)d_in[21];
  const float* bm1 = (const float*)d_in[22];
  const float* Wm2 = (const float*)d_in[23];
  const float* bm2 = (const float*)d_in[24];
  float* out = (float*)d_out;

  const int* src = ei;
  const int* dst = ei + E;

  char* wsb = (char*)d_ws;
  size_t off = 0;
  auto alloc = [&](size_t elems) -> void* {
    void* p = wsb + off;
    off += elems * 4;
    return p;
  };
  int* cnt = (int*)alloc(N);
  int* rowstart = (int*)alloc(N + 4);
  int* cursor = (int*)alloc(N);
  int* eidx = (int*)alloc(E);
  int2* pairs = (int2*)alloc((size_t)E * 2);  // bucket-grouped (src,dst)
  int* bhist = (int*)alloc(NBLK * 256 + 256);
  int* btot = (int*)alloc(256);
  int* bstart = (int*)alloc(256);
  float* dinv = (float*)alloc(N);
  float* gate = (float*)alloc(N);
  __half* hbuf = (__half*)alloc((size_t)N * 64);  // fp16 N x 128 plane
  short* ahi_p = (short*)alloc((size_t)N * 64);   // bf16-hi N x 128 plane
  short* alo_p = (short*)alloc((size_t)N * 64);   // bf16-lo N x 128 plane
  float* fbuf = (float*)alloc((size_t)N * 64);    // fp32 N x 64 (h3)
  int* bsum = (int*)alloc(256);
  int* boff = (int*)alloc(256);
  short* wt = (short*)alloc(49152);  // 98304 shorts
  float* bn1s = (float*)alloc(128);
  float* bn1h = (float*)alloc(128);
  float* bn2s = (float*)alloc(128);
  float* bn2h = (float*)alloc(128);
  float* pooledw = (float*)alloc(GG * 64);
  float* ssum = (float*)alloc(GG);
  unsigned* gmaxu = (unsigned*)alloc(GG);
  int* gstart = (int*)alloc(GG + 4);
  (void)ws_size;
  (void)n_in;
  (void)in_sizes;
  (void)out_size;

  const int nscan = (N + SB - 1) / SB;

  // CSR build (bucketed two-level scatter; reused for all 3 conv layers)
  hipMemsetAsync(cnt, 0, N * sizeof(int), stream);
  hipMemsetAsync(pooledw, 0, (GG * 64 + GG + GG) * sizeof(float), stream);
  k_count<<<(E + 255) / 256, 256, 0, stream>>>(dst, cnt, E);
  k_scan1<<<nscan, SB, 0, stream>>>(cnt, dinv, bsum, N);
  k_scan2<<<1, 256, 0, stream>>>(bsum, boff, nscan, rowstart + N);
  k_scan3<<<nscan, SB, 0, stream>>>(cnt, boff, rowstart, cursor, N);
  k_bhist<<<NBLK, 256, 0, stream>>>(dst, bhist, E);
  k_bscan1<<<256, 256, 0, stream>>>(bhist, btot);
  k_bscan2<<<1, 256, 0, stream>>>(btot, bstart);
  k_bscat<<<NBLK, 256, 0, stream>>>(src, dst, bhist, bstart, pairs, E);
  k_fill2<<<(E + 1023) / 1024, 256, 0, stream>>>(pairs, cursor, eidx, E);

  // weight/bn prep + graph bounds
  k_wsplit<<<192, 256, 0, stream>>>(W1, W2, W3, Wg1, wt);
  k_bnprep<<<1, 256, 0, stream>>>(g1, beta1, mean1, var1, g2, beta2, mean2,
                                  var2, bn1s, bn1h, bn2s, bn2h);
  k_gbounds<<<1, 128, 0, stream>>>(batch, gstart, N);

  const int gb = (N + 255) / 256;       // GEMM blocks (256 rows each)
  const int ab = (N * 64 + 255) / 256;  // agg blocks (wave per node)

  // Layer 1
  k_mgemm<128, 128, 0, 1, 0, 1><<<gb, 256, 0, stream>>>(
      x, nullptr, nullptr, wt, wt + 16384, dinv, nullptr, nullptr, nullptr,
      hbuf, nullptr, N);
  k_agg<128, 1><<<ab, 256, 0, stream>>>(hbuf, rowstart, eidx, dinv, b1, bn1s,
                                        bn1h, nullptr, ahi_p, alo_p, N);

  // Layer 2
  k_mgemm<128, 128, 1, 1, 0, 1><<<gb, 256, 0, stream>>>(
      nullptr, ahi_p, alo_p, wt + 32768, wt + 49152, dinv, nullptr, nullptr,
      nullptr, hbuf, nullptr, N);
  k_agg<128, 1><<<ab, 256, 0, stream>>>(hbuf, rowstart, eidx, dinv, b2, bn2s,
                                        bn2h, nullptr, ahi_p, alo_p, N);

  // Layer 3 (M=64)
  k_mgemm<128, 64, 1, 1, 0, 1><<<gb, 256, 0, stream>>>(
      nullptr, ahi_p, alo_p, wt + 65536, wt + 73728, dinv, nullptr, nullptr,
      nullptr, hbuf, nullptr, N);
  k_agg<64, 0><<<ab, 256, 0, stream>>>(hbuf, rowstart, eidx, dinv, b3, nullptr,
                                       nullptr, fbuf, nullptr, nullptr, N);

  // gate = relu(h3@Wg1+bg1)@Wg2+bg2 (fused epilogue)
  k_mgemm<64, 128, 0, 0, 1, 0><<<gb, 256, 0, stream>>>(
      fbuf, nullptr, nullptr, wt + 81920, wt + 90112, nullptr, bg1, Wg2, bg2,
      nullptr, gate, N);

  // softmax pooling
  k_pmax<<<GG * CPB, 256, 0, stream>>>(gate, gstart, gmaxu);
  k_psum<<<GG * CPB, 256, 0, stream>>>(gate, fbuf, gmaxu, gstart, pooledw,
                                       ssum);

  // head MLP
  k_head<<<1, 256, 0, stream>>>(pooledw, ssum, Wm1, bm1, Wm2, bm2, out);
}